// Round 3
// baseline (421.589 us; speedup 1.0000x reference)
//
#include <hip/hip_runtime.h>
#include <hip/hip_bf16.h>
#include <float.h>
#include <math.h>

#define NODE_DIM 256
#define HIDDEN   128
#define HEADS    8
#define HEAD_DIM 16
#define NB       768
#define BATCH    2

typedef __hip_bfloat16 bf16;

__device__ __forceinline__ float cvt(float x) { return x; }
__device__ __forceinline__ float cvt(bf16 x)  { return __bfloat162float(x); }

template <typename T> struct IsF32          { static constexpr int v = 0; };
template <>           struct IsF32<float>   { static constexpr int v = 1; };

__device__ __forceinline__ int ldmask(const void* m, int i, int bytem) {
  return bytem ? (int)((const unsigned char*)m)[i] : ((const int*)m)[i];
}

// ---- Detector: decide fp32-vs-bf16 for float tensors, int32-vs-byte for mask ----
__global__ void detect_kernel(const unsigned short* __restrict__ nf,
                              const unsigned* __restrict__ mw,
                              int* __restrict__ flags) {
  if (threadIdx.x == 0 && blockIdx.x == 0) {
    int f32 = 0;
    for (int i = 0; i < 4096; ++i) {
      int e = (nf[i] >> 7) & 0xFF;       // bf16 exponent field
      if (e >= 0x90) f32 = 1;            // impossible for N(0,1) bf16; certain for fp32 low halves
    }
    int bytem = 0;
    for (int i = 0; i < 384; ++i)        // 1536 bytes — safe under both layouts
      if (mw[i] > 1u) bytem = 1;         // byte-packed bools make words like 0x01010101
    flags[0] = f32;
    flags[1] = bytem;
  }
}

// ---------------- Kernel 1: QKV projection -> [b][h][n][d] fp32 ----------------
template <typename T>
__global__ __launch_bounds__(256) void qkv_kernel(
    const int* __restrict__ flags,
    const void* __restrict__ nf_, const void* __restrict__ Wq_,
    const void* __restrict__ Wk_, const void* __restrict__ Wv_,
    float* __restrict__ q, float* __restrict__ k, float* __restrict__ v) {
  if ((flags[0] != 0) != (IsF32<T>::v != 0)) return;
  const T* nf = (const T*)nf_;
  const T* Wq = (const T*)Wq_;
  const T* Wk = (const T*)Wk_;
  const T* Wv = (const T*)Wv_;
  int node = blockIdx.x;               // 0..BATCH*NB-1
  int b = node / NB, n = node % NB;
  int t = threadIdx.x;
  __shared__ float xs[NODE_DIM];
  xs[t] = cvt(nf[(size_t)node * NODE_DIM + t]);
  __syncthreads();
  for (int idx = t; idx < 3 * HIDDEN; idx += 256) {
    int m = idx >> 7, c = idx & 127;
    const T* W = (m == 0) ? Wq : (m == 1) ? Wk : Wv;
    float acc = 0.0f;
    for (int kk = 0; kk < NODE_DIM; ++kk)
      acc += xs[kk] * cvt(W[kk * HIDDEN + c]);
    int h = c >> 4, d = c & 15;
    float* dst = (m == 0) ? q : (m == 1) ? k : v;
    dst[(((b * HEADS + h) * NB) + n) * HEAD_DIM + d] = acc;
  }
}

// ---------------- Kernel 2: fold head-mean into W2 -> W2m (128x8), b2m (8) -----
template <typename T>
__global__ __launch_bounds__(256) void prep_kernel(
    const int* __restrict__ flags,
    const void* __restrict__ W2_, const void* __restrict__ b2_,
    float* __restrict__ W2m, float* __restrict__ b2m) {
  if ((flags[0] != 0) != (IsF32<T>::v != 0)) return;
  const T* W2 = (const T*)W2_;
  const T* b2 = (const T*)b2_;
  int t = threadIdx.x;
  for (int idx = t; idx < HIDDEN * HEADS; idx += 256) {
    int c = idx >> 3, h = idx & 7;
    float s = 0.0f;
    for (int d = 0; d < HEAD_DIM; ++d) s += cvt(W2[c * HIDDEN + h * HEAD_DIM + d]);
    W2m[c * HEADS + h] = s * (1.0f / 16.0f);
  }
  if (t < HEADS) {
    float s = 0.0f;
    for (int d = 0; d < HEAD_DIM; ++d) s += cvt(b2[t * HEAD_DIM + d]);
    b2m[t] = s * (1.0f / 16.0f);
  }
}

// ------- Kernel 3: fused edge-geometry MLP bias + masked softmax attention -----
template <typename T>
__global__ __launch_bounds__(256) void attn_kernel(
    const int* __restrict__ flags,
    const void* __restrict__ pos_, const void* __restrict__ mask_,
    const void* __restrict__ W1_, const void* __restrict__ b1_,
    const float* __restrict__ W2m, const float* __restrict__ b2m,
    const float* __restrict__ q, const float* __restrict__ k,
    const float* __restrict__ v, float* __restrict__ agg) {
  if ((flags[0] != 0) != (IsF32<T>::v != 0)) return;
  const T* pos = (const T*)pos_;
  const T* W1  = (const T*)W1_;
  const T* b1  = (const T*)b1_;
  int bytem = flags[1];
  int node = blockIdx.x;
  int b = node / NB, i = node % NB;
  int t = threadIdx.x;

  __shared__ float sc[HEADS][NB];        // 24 KB score/weight buffer
  __shared__ float qs[HIDDEN];
  __shared__ float W1s[3][HIDDEN];
  __shared__ float b1s[HIDDEN];
  __shared__ float W2ms[HIDDEN * HEADS];
  __shared__ float b2ms[HEADS];
  __shared__ float invs[HEADS];
  __shared__ float part[2][HIDDEN];

  if (t < HIDDEN) {
    int h = t >> 4, d = t & 15;
    qs[t] = q[((b * HEADS + h) * NB + i) * HEAD_DIM + d];
    b1s[t] = cvt(b1[t]);
  }
  for (int idx = t; idx < 3 * HIDDEN; idx += 256)
    W1s[idx >> 7][idx & 127] = cvt(W1[idx]);
  for (int idx = t; idx < HIDDEN * HEADS; idx += 256)
    W2ms[idx] = W2m[idx];
  if (t < HEADS) b2ms[t] = b2m[t];

  float pix = cvt(pos[(b * NB + i) * 2]);
  float piy = cvt(pos[(b * NB + i) * 2 + 1]);
  float mi  = (float)(ldmask(mask_, b * NB + i, bytem) != 0);
  __syncthreads();

  // ---- pass 1: scores (bias + q.k) ----
  for (int j = t; j < NB; j += 256) {
    float s8[HEADS];
    if (ldmask(mask_, b * NB + j, bytem) != 0) {
      float dx = pix - cvt(pos[(b * NB + j) * 2]);
      float dy = piy - cvt(pos[(b * NB + j) * 2 + 1]);
      float sq = dx * dx + dy * dy;
      float dist = sqrtf(sq + 1e-6f);
      float nrm  = sqrtf(sq);
      float dn   = fmaxf(nrm, 1e-6f);
      float ux = dx / dn, uy = dy / dn;
      float bias[HEADS];
#pragma unroll
      for (int h = 0; h < HEADS; ++h) bias[h] = b2ms[h];
      for (int c = 0; c < HIDDEN; ++c) {
        float u = ux * W1s[0][c] + uy * W1s[1][c] + dist * W1s[2][c] + b1s[c];
        float g = 0.5f * u * (1.0f + erff(u * 0.70710678118654752f));
        const float* wrow = &W2ms[c * HEADS];
#pragma unroll
        for (int h = 0; h < HEADS; ++h) bias[h] += g * wrow[h];
      }
#pragma unroll
      for (int h = 0; h < HEADS; ++h) {
        const float* kr = &k[((b * HEADS + h) * NB + j) * HEAD_DIM];
        float dot = 0.0f;
#pragma unroll
        for (int d = 0; d < HEAD_DIM; ++d) dot += qs[h * HEAD_DIM + d] * kr[d];
        s8[h] = dot * 0.25f + bias[h];
      }
    } else {
#pragma unroll
      for (int h = 0; h < HEADS; ++h) s8[h] = -FLT_MAX;
    }
#pragma unroll
    for (int h = 0; h < HEADS; ++h) sc[h][j] = s8[h];
  }
  __syncthreads();

  // ---- softmax per head: 8 groups of 32 lanes ----
  {
    int h = t >> 5;
    int lane = t & 31;
    float m = -FLT_MAX;
    for (int j = lane; j < NB; j += 32) m = fmaxf(m, sc[h][j]);
    for (int off = 16; off; off >>= 1) m = fmaxf(m, __shfl_down(m, off, 32));
    m = __shfl(m, 0, 32);
    float s = 0.0f;
    for (int j = lane; j < NB; j += 32) {
      float sv = sc[h][j];
      float e = (sv == -FLT_MAX) ? 0.0f : expf(sv - m);
      sc[h][j] = e;
      s += e;
    }
    for (int off = 16; off; off >>= 1) s += __shfl_down(s, off, 32);
    if (lane == 0)
      invs[h] = (m > -0.5f * FLT_MAX && s > 0.0f) ? (mi / s) : 0.0f;
  }
  __syncthreads();

  // ---- pass 2: agg[h][d] = (sum_j e_j * v_j) * invs[h] ----
  {
    int o = t & 127;
    int half = t >> 7;
    int h = o >> 4, d = o & 15;
    const float* vb = &v[((size_t)(b * HEADS + h) * NB) * HEAD_DIM + d];
    float acc = 0.0f;
    int j0 = half * (NB / 2), j1 = j0 + NB / 2;
    for (int j = j0; j < j1; ++j) acc += sc[h][j] * vb[(size_t)j * HEAD_DIM];
    part[half][o] = acc;
  }
  __syncthreads();
  if (t < HIDDEN) {
    int h = t >> 4;
    agg[(size_t)node * HIDDEN + t] = (part[0][t] + part[1][t]) * invs[h];
  }
}

// -------- Kernel 4: out proj + residual + mask + LayerNorm -> fp32 out ---------
template <typename T>
__global__ __launch_bounds__(256) void out_kernel(
    const int* __restrict__ flags,
    const float* __restrict__ agg, const void* __restrict__ nf_,
    const void* __restrict__ mask_, const void* __restrict__ Wo_,
    const void* __restrict__ bo_, const void* __restrict__ gamma_,
    const void* __restrict__ beta_, float* __restrict__ out) {
  if ((flags[0] != 0) != (IsF32<T>::v != 0)) return;
  const T* nf    = (const T*)nf_;
  const T* Wo    = (const T*)Wo_;
  const T* bo    = (const T*)bo_;
  const T* gamma = (const T*)gamma_;
  const T* beta  = (const T*)beta_;
  int bytem = flags[1];
  int node = blockIdx.x;
  int t = threadIdx.x;              // 256 = NODE_DIM
  __shared__ float as[HIDDEN];
  __shared__ float ws_[4], ws2_[4];
  if (t < HIDDEN) as[t] = agg[(size_t)node * HIDDEN + t];
  __syncthreads();
  float y = cvt(bo[t]);
  for (int kk = 0; kk < HIDDEN; ++kk)
    y += as[kk] * cvt(Wo[kk * NODE_DIM + t]);
  float mi = (float)(ldmask(mask_, node, bytem) != 0);
  float x = mi * (cvt(nf[(size_t)node * NODE_DIM + t]) + y);
  float s = x, s2 = x * x;
  for (int off = 32; off; off >>= 1) {
    s += __shfl_down(s, off, 64);
    s2 += __shfl_down(s2, off, 64);
  }
  int w = t >> 6, lane = t & 63;
  if (lane == 0) { ws_[w] = s; ws2_[w] = s2; }
  __syncthreads();
  s  = ws_[0] + ws_[1] + ws_[2] + ws_[3];
  s2 = ws2_[0] + ws2_[1] + ws2_[2] + ws2_[3];
  float mu = s * (1.0f / NODE_DIM);
  float var = fmaxf(s2 * (1.0f / NODE_DIM) - mu * mu, 0.0f);
  float o = (x - mu) * rsqrtf(var + 1e-5f) * cvt(gamma[t]) + cvt(beta[t]);
  out[(size_t)node * NODE_DIM + t] = o;
}

extern "C" void kernel_launch(void* const* d_in, const int* in_sizes, int n_in,
                              void* d_out, int out_size, void* d_ws, size_t ws_size,
                              hipStream_t stream) {
  const void* nf    = d_in[0];
  const void* pos   = d_in[1];
  const void* mask  = d_in[2];
  const void* Wq    = d_in[3];
  const void* Wk    = d_in[4];
  const void* Wv    = d_in[5];
  const void* W1    = d_in[6];
  const void* b1    = d_in[7];
  const void* W2    = d_in[8];
  const void* b2    = d_in[9];
  const void* Wo    = d_in[10];
  const void* bo    = d_in[11];
  const void* gamma = d_in[12];
  const void* beta  = d_in[13];

  const int NNODES = BATCH * NB;                  // 1536
  const int QKV = BATCH * HEADS * NB * HEAD_DIM;  // 196608

  int*   flags = (int*)d_ws;
  float* ws    = (float*)d_ws + 16;
  float* q   = ws;
  float* k   = q + QKV;
  float* v   = k + QKV;
  float* W2m = v + QKV;               // 1024
  float* b2m = W2m + HIDDEN * HEADS;  // 8
  float* agg = b2m + HEADS;           // 1536*128

  detect_kernel<<<1, 64, 0, stream>>>((const unsigned short*)nf,
                                      (const unsigned*)mask, flags);

  qkv_kernel<bf16> <<<NNODES, 256, 0, stream>>>(flags, nf, Wq, Wk, Wv, q, k, v);
  qkv_kernel<float><<<NNODES, 256, 0, stream>>>(flags, nf, Wq, Wk, Wv, q, k, v);
  prep_kernel<bf16> <<<1, 256, 0, stream>>>(flags, W2, b2, W2m, b2m);
  prep_kernel<float><<<1, 256, 0, stream>>>(flags, W2, b2, W2m, b2m);
  attn_kernel<bf16> <<<NNODES, 256, 0, stream>>>(flags, pos, mask, W1, b1, W2m,
                                                 b2m, q, k, v, agg);
  attn_kernel<float><<<NNODES, 256, 0, stream>>>(flags, pos, mask, W1, b1, W2m,
                                                 b2m, q, k, v, agg);
  out_kernel<bf16> <<<NNODES, 256, 0, stream>>>(flags, agg, nf, mask, Wo, bo,
                                                gamma, beta, (float*)d_out);
  out_kernel<float><<<NNODES, 256, 0, stream>>>(flags, agg, nf, mask, Wo, bo,
                                                gamma, beta, (float*)d_out);
}

// Round 4
// 296.090 us; speedup vs baseline: 1.4239x; 1.4239x over previous
//
#include <hip/hip_runtime.h>
#include <float.h>
#include <math.h>

#define NODE_DIM 256
#define HIDDEN   128
#define HEADS    8
#define HEAD_DIM 16
#define NB       768
#define BATCH    2
#define NNODES   (BATCH * NB)

// ---------------- Kernel 1: QKV projection, 4 nodes/block -> [node][128] -------
__global__ __launch_bounds__(256) void qkv_kernel(
    const float* __restrict__ nf, const float* __restrict__ Wq,
    const float* __restrict__ Wk, const float* __restrict__ Wv,
    float* __restrict__ q, float* __restrict__ k, float* __restrict__ v) {
  int n0 = blockIdx.x * 4;
  int t = threadIdx.x;
  for (int idx = t; idx < 3 * HIDDEN; idx += 256) {
    int m = idx >> 7, c = idx & 127;
    const float* W = (m == 0) ? Wq : (m == 1) ? Wk : Wv;
    float* dst     = (m == 0) ? q  : (m == 1) ? k  : v;
    float a0 = 0.f, a1 = 0.f, a2 = 0.f, a3 = 0.f;
    const float* x0 = nf + (size_t)(n0 + 0) * NODE_DIM;
    const float* x1 = nf + (size_t)(n0 + 1) * NODE_DIM;
    const float* x2 = nf + (size_t)(n0 + 2) * NODE_DIM;
    const float* x3 = nf + (size_t)(n0 + 3) * NODE_DIM;
#pragma unroll 8
    for (int kk = 0; kk < NODE_DIM; ++kk) {
      float w = W[kk * HIDDEN + c];       // coalesced vector load
      a0 = fmaf(x0[kk], w, a0);           // x*: wave-uniform -> s_load
      a1 = fmaf(x1[kk], w, a1);
      a2 = fmaf(x2[kk], w, a2);
      a3 = fmaf(x3[kk], w, a3);
    }
    dst[(size_t)(n0 + 0) * HIDDEN + c] = a0;
    dst[(size_t)(n0 + 1) * HIDDEN + c] = a1;
    dst[(size_t)(n0 + 2) * HIDDEN + c] = a2;
    dst[(size_t)(n0 + 3) * HIDDEN + c] = a3;
  }
}

// ------- Kernel 2: pack P[c][16] = {W1x,W1y,W1d,b1, W2m[0..7], pad} + b2m ------
__global__ __launch_bounds__(256) void prep_kernel(
    const float* __restrict__ W1, const float* __restrict__ b1,
    const float* __restrict__ W2, const float* __restrict__ b2,
    float* __restrict__ P, float* __restrict__ b2m) {
  int t = threadIdx.x;
  __shared__ float w2s[HIDDEN * HEADS];
  for (int idx = t; idx < HIDDEN * HEADS; idx += 256) {
    int c = idx >> 3, h = idx & 7;
    float s = 0.0f;
    for (int d = 0; d < HEAD_DIM; ++d) s += W2[c * HIDDEN + h * HEAD_DIM + d];
    w2s[c * HEADS + h] = s * (1.0f / 16.0f);
  }
  if (t < HEADS) {
    float s = 0.0f;
    for (int d = 0; d < HEAD_DIM; ++d) s += b2[t * HEAD_DIM + d];
    b2m[t] = s * (1.0f / 16.0f);
  }
  __syncthreads();
  if (t < HIDDEN) {
    float* Pr = P + t * 16;
    Pr[0] = W1[0 * HIDDEN + t];
    Pr[1] = W1[1 * HIDDEN + t];
    Pr[2] = W1[2 * HIDDEN + t];
    Pr[3] = b1[t];
#pragma unroll
    for (int h = 0; h < HEADS; ++h) Pr[4 + h] = w2s[t * HEADS + h];
    Pr[12] = Pr[13] = Pr[14] = Pr[15] = 0.0f;
  }
}

// ------- Kernel 3: fused edge-bias + masked softmax attention, 1 block/query --
__global__ __launch_bounds__(256) void attn_kernel(
    const float* __restrict__ pos, const int* __restrict__ mask,
    const float* __restrict__ P, const float* __restrict__ b2m,
    const float* __restrict__ q, const float* __restrict__ k,
    const float* __restrict__ v, float* __restrict__ agg) {
  int node = blockIdx.x;
  int b = node / NB, i = node % NB;
  int t = threadIdx.x;

  // masked query: agg = 0 (out_kernel then produces beta, per reference)
  if (mask[node] == 0) {
    if (t < HIDDEN) agg[(size_t)node * HIDDEN + t] = 0.0f;
    return;
  }

  __shared__ float sE[HEADS * NB];      // compacted scores/weights, stride NB
  __shared__ int   vj[NB];
  __shared__ int   nvs;
  __shared__ float qs[HIDDEN];
  __shared__ float invs[HEADS];
  __shared__ float part[2][HIDDEN];

  if (t == 0) nvs = 0;
  if (t < HIDDEN) qs[t] = q[(size_t)node * HIDDEN + t];
  __syncthreads();
  for (int j = t; j < NB; j += 256)
    if (mask[b * NB + j] != 0) { int s = atomicAdd(&nvs, 1); vj[s] = j; }
  __syncthreads();
  int nv = nvs;

  float pix = pos[(b * NB + i) * 2];
  float piy = pos[(b * NB + i) * 2 + 1];
  float bb[HEADS];
#pragma unroll
  for (int h = 0; h < HEADS; ++h) bb[h] = b2m[h];    // uniform -> SGPR

  const float4* q4 = (const float4*)qs;

  // ---- pass 1: per valid key, edge-MLP bias (tanh-GELU) + q.k ----
  for (int jj = t; jj < nv; jj += 256) {
    int j = vj[jj];
    float dx = pix - pos[(b * NB + j) * 2];
    float dy = piy - pos[(b * NB + j) * 2 + 1];
    float sq = dx * dx + dy * dy;
    float dist = sqrtf(sq + 1e-6f);
    float dn = fmaxf(sqrtf(sq), 1e-6f);
    float ux = dx / dn, uy = dy / dn;

    float bias[HEADS];
#pragma unroll
    for (int h = 0; h < HEADS; ++h) bias[h] = bb[h];

    for (int c = 0; c < HIDDEN; ++c) {
      const float4* Pc = (const float4*)(P + (c << 4));   // uniform -> s_load
      float4 p0 = Pc[0], p1 = Pc[1], p2 = Pc[2];
      float u  = fmaf(ux, p0.x, fmaf(uy, p0.y, fmaf(dist, p0.z, p0.w)));
      float u2 = u * u;
      float tt = u * fmaf(u2, 0.0356774081f, 0.7978845608f);  // t = 0.79788*(u+0.044715u^3)
      float g  = u / (1.0f + __expf(-2.0f * tt));             // u * sigmoid(2t)
      bias[0] = fmaf(g, p1.x, bias[0]);
      bias[1] = fmaf(g, p1.y, bias[1]);
      bias[2] = fmaf(g, p1.z, bias[2]);
      bias[3] = fmaf(g, p1.w, bias[3]);
      bias[4] = fmaf(g, p2.x, bias[4]);
      bias[5] = fmaf(g, p2.y, bias[5]);
      bias[6] = fmaf(g, p2.z, bias[6]);
      bias[7] = fmaf(g, p2.w, bias[7]);
    }

    const float4* kr = (const float4*)(k + (size_t)(b * NB + j) * HIDDEN);
#pragma unroll
    for (int h = 0; h < HEADS; ++h) {
      float dot = 0.0f;
#pragma unroll
      for (int r = 0; r < 4; ++r) {
        float4 a = q4[h * 4 + r];
        float4 kb = kr[h * 4 + r];
        dot += a.x * kb.x + a.y * kb.y + a.z * kb.z + a.w * kb.w;
      }
      sE[h * NB + jj] = fmaf(dot, 0.25f, bias[h]);
    }
  }
  __syncthreads();

  // ---- softmax per head over compacted [0,nv) : 8 groups of 32 lanes ----
  {
    int h = t >> 5, lane = t & 31;
    float m = -FLT_MAX;
    for (int jj = lane; jj < nv; jj += 32) m = fmaxf(m, sE[h * NB + jj]);
    for (int off = 16; off; off >>= 1) m = fmaxf(m, __shfl_down(m, off, 32));
    m = __shfl(m, 0, 32);
    float s = 0.0f;
    for (int jj = lane; jj < nv; jj += 32) {
      float e = __expf(sE[h * NB + jj] - m);
      sE[h * NB + jj] = e;
      s += e;
    }
    for (int off = 16; off; off >>= 1) s += __shfl_down(s, off, 32);
    if (lane == 0) invs[h] = (nv > 0) ? (1.0f / s) : 0.0f;
  }
  __syncthreads();

  // ---- pass 2: agg[o] = sum_jj w * v[vj[jj]][o] ----
  {
    int o = t & 127, half = t >> 7;
    int h = o >> 4;
    float acc = 0.0f;
    for (int jj = half; jj < nv; jj += 2) {
      int j = vj[jj];
      acc = fmaf(sE[h * NB + jj], v[(size_t)(b * NB + j) * HIDDEN + o], acc);
    }
    part[half][o] = acc;
  }
  __syncthreads();
  if (t < HIDDEN)
    agg[(size_t)node * HIDDEN + t] = (part[0][t] + part[1][t]) * invs[t >> 4];
}

// -------- Kernel 4: out proj + residual + mask + LayerNorm, 4 nodes/block ------
__global__ __launch_bounds__(256) void out_kernel(
    const float* __restrict__ agg, const float* __restrict__ nf,
    const int* __restrict__ mask, const float* __restrict__ Wo,
    const float* __restrict__ bo, const float* __restrict__ gamma,
    const float* __restrict__ beta, float* __restrict__ out) {
  int n0 = blockIdx.x * 4;
  int t = threadIdx.x;                  // 256 = NODE_DIM
  float bv = bo[t];
  float acc[4] = {bv, bv, bv, bv};
  const float* a0 = agg + (size_t)(n0 + 0) * HIDDEN;
  const float* a1 = agg + (size_t)(n0 + 1) * HIDDEN;
  const float* a2 = agg + (size_t)(n0 + 2) * HIDDEN;
  const float* a3 = agg + (size_t)(n0 + 3) * HIDDEN;
#pragma unroll 8
  for (int kk = 0; kk < HIDDEN; ++kk) {
    float w = Wo[kk * NODE_DIM + t];    // coalesced
    acc[0] = fmaf(a0[kk], w, acc[0]);   // a*: uniform -> s_load
    acc[1] = fmaf(a1[kk], w, acc[1]);
    acc[2] = fmaf(a2[kk], w, acc[2]);
    acc[3] = fmaf(a3[kk], w, acc[3]);
  }
  float gv = gamma[t], btv = beta[t];
  __shared__ float rs[4][4], rs2[4][4];
  float xv[4];
#pragma unroll
  for (int n = 0; n < 4; ++n) {
    float mi = (float)(mask[n0 + n] != 0);
    float x = mi * (nf[(size_t)(n0 + n) * NODE_DIM + t] + acc[n]);
    xv[n] = x;
    float s = x, s2 = x * x;
    for (int off = 32; off; off >>= 1) {
      s += __shfl_down(s, off, 64);
      s2 += __shfl_down(s2, off, 64);
    }
    if ((t & 63) == 0) { rs[n][t >> 6] = s; rs2[n][t >> 6] = s2; }
  }
  __syncthreads();
#pragma unroll
  for (int n = 0; n < 4; ++n) {
    float s  = rs[n][0] + rs[n][1] + rs[n][2] + rs[n][3];
    float s2 = rs2[n][0] + rs2[n][1] + rs2[n][2] + rs2[n][3];
    float mu = s * (1.0f / NODE_DIM);
    float var = fmaxf(s2 * (1.0f / NODE_DIM) - mu * mu, 0.0f);
    out[(size_t)(n0 + n) * NODE_DIM + t] =
        (xv[n] - mu) * rsqrtf(var + 1e-5f) * gv + btv;
  }
}

extern "C" void kernel_launch(void* const* d_in, const int* in_sizes, int n_in,
                              void* d_out, int out_size, void* d_ws, size_t ws_size,
                              hipStream_t stream) {
  const float* nf    = (const float*)d_in[0];
  const float* pos   = (const float*)d_in[1];
  const int*   mask  = (const int*)  d_in[2];
  const float* Wq    = (const float*)d_in[3];
  const float* Wk    = (const float*)d_in[4];
  const float* Wv    = (const float*)d_in[5];
  const float* W1    = (const float*)d_in[6];
  const float* b1    = (const float*)d_in[7];
  const float* W2    = (const float*)d_in[8];
  const float* b2    = (const float*)d_in[9];
  const float* Wo    = (const float*)d_in[10];
  const float* bo    = (const float*)d_in[11];
  const float* gamma = (const float*)d_in[12];
  const float* beta  = (const float*)d_in[13];

  const int QKV = NNODES * HIDDEN;      // 196608

  float* ws  = (float*)d_ws;
  float* q   = ws;
  float* k   = q + QKV;
  float* v   = k + QKV;
  float* P   = v + QKV;                 // 128*16 = 2048
  float* b2m = P + HIDDEN * 16;         // 8
  float* agg = b2m + 8;                 // NNODES*128

  qkv_kernel <<<NNODES / 4, 256, 0, stream>>>(nf, Wq, Wk, Wv, q, k, v);
  prep_kernel<<<1,          256, 0, stream>>>(W1, b1, W2, b2, P, b2m);
  attn_kernel<<<NNODES,     256, 0, stream>>>(pos, mask, P, b2m, q, k, v, agg);
  out_kernel <<<NNODES / 4, 256, 0, stream>>>(agg, nf, mask, Wo, bo, gamma, beta,
                                              (float*)d_out);
}

// Round 5
// 228.221 us; speedup vs baseline: 1.8473x; 1.2974x over previous
//
#include <hip/hip_runtime.h>
#include <float.h>
#include <math.h>

#define NODE_DIM 256
#define HIDDEN   128
#define HEADS    8
#define HEAD_DIM 16
#define NB       768
#define BATCH    2
#define NNODES   (BATCH * NB)
#define QT       2            // queries per attn block (LDS-limited: sE = QT*8*768*4 B)

__device__ __forceinline__ float gelu_t(float u) {
  float u2 = u * u;
  float tt = u * fmaf(u2, 0.0356774081f, 0.7978845608f);
  return u / (1.0f + __expf(-2.0f * tt));
}

// ---------------- K1: QKV projection, 8 nodes/block; also zero agg for masked --
__global__ __launch_bounds__(256) void qkv_kernel(
    const float* __restrict__ nf, const float* __restrict__ Wq,
    const float* __restrict__ Wk, const float* __restrict__ Wv,
    const int* __restrict__ mask,
    float* __restrict__ q, float* __restrict__ k, float* __restrict__ v,
    float* __restrict__ agg) {
  int n0 = blockIdx.x * 8;
  int t = threadIdx.x;
  __shared__ float4 xs4[8][64];          // 8 node rows of 256 floats
  for (int idx = t; idx < 512; idx += 256) {
    int n = idx >> 6, e = idx & 63;
    xs4[n][e] = ((const float4*)(nf + (size_t)(n0 + n) * NODE_DIM))[e];
  }
  __syncthreads();
  for (int idx = t; idx < 3 * HIDDEN; idx += 256) {
    int m = idx >> 7, c = idx & 127;
    const float* W = (m == 0) ? Wq : (m == 1) ? Wk : Wv;
    float* dst     = (m == 0) ? q  : (m == 1) ? k  : v;
    float acc[8] = {0.f, 0.f, 0.f, 0.f, 0.f, 0.f, 0.f, 0.f};
    for (int kg = 0; kg < 64; ++kg) {
      float w0 = W[(kg * 4 + 0) * HIDDEN + c];   // coalesced across c
      float w1 = W[(kg * 4 + 1) * HIDDEN + c];
      float w2 = W[(kg * 4 + 2) * HIDDEN + c];
      float w3 = W[(kg * 4 + 3) * HIDDEN + c];
#pragma unroll
      for (int n = 0; n < 8; ++n) {
        float4 x = xs4[n][kg];                   // LDS b128 broadcast
        acc[n] = fmaf(x.x, w0, fmaf(x.y, w1, fmaf(x.z, w2, fmaf(x.w, w3, acc[n]))));
      }
    }
#pragma unroll
    for (int n = 0; n < 8; ++n)
      dst[(size_t)(n0 + n) * HIDDEN + c] = acc[n];
  }
  // masked nodes never touched by attn: zero their agg rows here
  for (int idx = t; idx < 8 * HIDDEN; idx += 256) {
    int n = idx >> 7;
    if (mask[n0 + n] == 0)
      agg[(size_t)(n0 + n) * HIDDEN + (idx & 127)] = 0.0f;
  }
}

// ------- K2: pack P[c][16] = {W1x,W1y,W1d,b1, W2m[0..7], pad} + b2m ------------
__global__ __launch_bounds__(256) void prep_kernel(
    const float* __restrict__ W1, const float* __restrict__ b1,
    const float* __restrict__ W2, const float* __restrict__ b2,
    float* __restrict__ P, float* __restrict__ b2m) {
  int t = threadIdx.x;
  __shared__ float w2s[HIDDEN * HEADS];
  for (int idx = t; idx < HIDDEN * HEADS; idx += 256) {
    int c = idx >> 3, h = idx & 7;
    float s = 0.0f;
    for (int d = 0; d < HEAD_DIM; ++d) s += W2[c * HIDDEN + h * HEAD_DIM + d];
    w2s[c * HEADS + h] = s * (1.0f / 16.0f);
  }
  if (t < HEADS) {
    float s = 0.0f;
    for (int d = 0; d < HEAD_DIM; ++d) s += b2[t * HEAD_DIM + d];
    b2m[t] = s * (1.0f / 16.0f);
  }
  __syncthreads();
  if (t < HIDDEN) {
    float* Pr = P + t * 16;
    Pr[0] = W1[0 * HIDDEN + t];
    Pr[1] = W1[1 * HIDDEN + t];
    Pr[2] = W1[2 * HIDDEN + t];
    Pr[3] = b1[t];
#pragma unroll
    for (int h = 0; h < HEADS; ++h) Pr[4 + h] = w2s[t * HEADS + h];
    Pr[12] = Pr[13] = Pr[14] = Pr[15] = 0.0f;
  }
}

// ------- K3: per-batch valid-node compaction (queries == keys share the mask) --
__global__ __launch_bounds__(256) void compact_kernel(
    const int* __restrict__ mask, const float* __restrict__ pos,
    int* __restrict__ vlist, int* __restrict__ cnt,
    float* __restrict__ pcx, float* __restrict__ pcy) {
  int b = blockIdx.x, t = threadIdx.x;
  __shared__ int cs;
  __shared__ int lst[NB];
  if (t == 0) cs = 0;
  __syncthreads();
  for (int j = t; j < NB; j += 256)
    if (mask[b * NB + j] != 0) { int p = atomicAdd(&cs, 1); lst[p] = j; }
  __syncthreads();
  int nvb = cs;
  if (t == 0) cnt[b] = nvb;
  for (int idx = t; idx < nvb; idx += 256) {
    int j = lst[idx];
    vlist[b * NB + idx] = j;
    pcx[b * NB + idx] = pos[(b * NB + j) * 2];
    pcy[b * NB + idx] = pos[(b * NB + j) * 2 + 1];
  }
}

// ------- K4: fused edge-bias + attention, QT active queries per block ----------
__global__ __launch_bounds__(256) void attn_kernel(
    const float* __restrict__ pcx, const float* __restrict__ pcy,
    const int* __restrict__ vlist, const int* __restrict__ cnt,
    const float* __restrict__ P, const float* __restrict__ b2m,
    const float* __restrict__ qg, const float* __restrict__ kg,
    const float* __restrict__ vg, float* __restrict__ agg) {
  int r = blockIdx.x;
  int b = r & 1, blk = r >> 1;              // batch-interleaved for CU balance
  int nv = cnt[b];
  int base = blk * QT;
  if (base >= nv) return;
  int qn = (nv - base < QT) ? (nv - base) : QT;
  int t = threadIdx.x;

  __shared__ float sE[QT * HEADS][NB];      // 49152 B
  __shared__ float4 Ps4[HIDDEN * 4];        //  8192 B (P as float4 rows)
  __shared__ __align__(16) float qs[QT][HIDDEN];  // 1024 B
  __shared__ int   vjs[NB];                 //  3072 B
  __shared__ float part[2][QT][HIDDEN];     //  2048 B
  __shared__ float invs[QT][HEADS];         //    64 B

  for (int idx = t; idx < HIDDEN * 4; idx += 256)
    Ps4[idx] = ((const float4*)P)[idx];
  for (int idx = t; idx < nv; idx += 256)
    vjs[idx] = vlist[b * NB + idx];

  int qid0 = vlist[b * NB + base];
  int qid1 = vlist[b * NB + base + (qn > 1 ? 1 : 0)];
  for (int idx = t; idx < QT * HIDDEN; idx += 256) {
    int qq = idx >> 7;
    int nid = b * NB + (qq ? qid1 : qid0);
    qs[qq][idx & 127] = qg[(size_t)nid * HIDDEN + (idx & 127)];
  }
  float pix0 = pcx[b * NB + base], piy0 = pcy[b * NB + base];
  int i1 = base + (qn > 1 ? 1 : 0);
  float pix1 = pcx[b * NB + i1], piy1 = pcy[b * NB + i1];
  float b2mv = b2m[t & 7];
  __syncthreads();

  // ---- phase 1a: qk dots; threads = (h = t&7, jj strided 32) ----
  {
    int h = t & 7;
    for (int jj = t >> 3; jj < nv; jj += 32) {
      int j = vjs[jj];
      const float4* kr = (const float4*)(kg + ((size_t)(b * NB + j)) * HIDDEN + h * 16);
      float4 k0 = kr[0], k1 = kr[1], k2 = kr[2], k3 = kr[3];
#pragma unroll
      for (int qq = 0; qq < QT; ++qq) {
        const float4* qp = (const float4*)&qs[qq][h * 16];
        float4 a0 = qp[0], a1 = qp[1], a2 = qp[2], a3 = qp[3];
        float d = a0.x * k0.x + a0.y * k0.y + a0.z * k0.z + a0.w * k0.w +
                  a1.x * k1.x + a1.y * k1.y + a1.z * k1.z + a1.w * k1.w +
                  a2.x * k2.x + a2.y * k2.y + a2.z * k2.z + a2.w * k2.w +
                  a3.x * k3.x + a3.y * k3.y + a3.z * k3.z + a3.w * k3.w;
        if (qq < qn) sE[qq * HEADS + h][jj] = fmaf(d, 0.25f, b2mv);
      }
    }
  }
  __syncthreads();

  // ---- phase 1b: edge-MLP bias; thread owns key jj, P from LDS b128 broadcast -
  for (int jj = t; jj < nv; jj += 256) {
    float px = pcx[b * NB + jj], py = pcy[b * NB + jj];
    float ux0, uy0, d0, ux1, uy1, d1;
    {
      float dx = pix0 - px, dy = piy0 - py;
      float sq = dx * dx + dy * dy;
      d0 = sqrtf(sq + 1e-6f);
      float dn = fmaxf(sqrtf(sq), 1e-6f);
      ux0 = dx / dn; uy0 = dy / dn;
    }
    {
      float dx = pix1 - px, dy = piy1 - py;
      float sq = dx * dx + dy * dy;
      d1 = sqrtf(sq + 1e-6f);
      float dn = fmaxf(sqrtf(sq), 1e-6f);
      ux1 = dx / dn; uy1 = dy / dn;
    }
    float bias[QT][8] = {};
    for (int c = 0; c < HIDDEN; ++c) {
      float4 p0 = Ps4[c * 4 + 0];
      float4 p1 = Ps4[c * 4 + 1];
      float4 p2 = Ps4[c * 4 + 2];
      float u0 = fmaf(ux0, p0.x, fmaf(uy0, p0.y, fmaf(d0, p0.z, p0.w)));
      float g0 = gelu_t(u0);
      bias[0][0] = fmaf(g0, p1.x, bias[0][0]);
      bias[0][1] = fmaf(g0, p1.y, bias[0][1]);
      bias[0][2] = fmaf(g0, p1.z, bias[0][2]);
      bias[0][3] = fmaf(g0, p1.w, bias[0][3]);
      bias[0][4] = fmaf(g0, p2.x, bias[0][4]);
      bias[0][5] = fmaf(g0, p2.y, bias[0][5]);
      bias[0][6] = fmaf(g0, p2.z, bias[0][6]);
      bias[0][7] = fmaf(g0, p2.w, bias[0][7]);
      float u1 = fmaf(ux1, p0.x, fmaf(uy1, p0.y, fmaf(d1, p0.z, p0.w)));
      float g1 = gelu_t(u1);
      bias[1][0] = fmaf(g1, p1.x, bias[1][0]);
      bias[1][1] = fmaf(g1, p1.y, bias[1][1]);
      bias[1][2] = fmaf(g1, p1.z, bias[1][2]);
      bias[1][3] = fmaf(g1, p1.w, bias[1][3]);
      bias[1][4] = fmaf(g1, p2.x, bias[1][4]);
      bias[1][5] = fmaf(g1, p2.y, bias[1][5]);
      bias[1][6] = fmaf(g1, p2.z, bias[1][6]);
      bias[1][7] = fmaf(g1, p2.w, bias[1][7]);
    }
#pragma unroll
    for (int qq = 0; qq < QT; ++qq)
      if (qq < qn) {
#pragma unroll
        for (int h = 0; h < 8; ++h)
          sE[qq * HEADS + h][jj] += bias[qq][h];
      }
  }
  __syncthreads();

  // ---- softmax per (q,h): 8 groups of 32 lanes, loop over q ----
  for (int qq = 0; qq < qn; ++qq) {
    int h = t >> 5, lane = t & 31;
    float* row = &sE[qq * HEADS + h][0];
    float m = -FLT_MAX;
    for (int jj = lane; jj < nv; jj += 32) m = fmaxf(m, row[jj]);
    for (int off = 16; off; off >>= 1) m = fmaxf(m, __shfl_down(m, off, 32));
    m = __shfl(m, 0, 32);
    float s = 0.0f;
    for (int jj = lane; jj < nv; jj += 32) {
      float e = __expf(row[jj] - m);
      row[jj] = e;
      s += e;
    }
    for (int off = 16; off; off >>= 1) s += __shfl_down(s, off, 32);
    if (lane == 0) invs[qq][h] = 1.0f / s;
  }
  __syncthreads();

  // ---- pass 2: weighted V accumulation ----
  {
    int o = t & 127, half = t >> 7, h = o >> 4;
    float a0 = 0.f, a1 = 0.f;
    for (int jj = half; jj < nv; jj += 2) {
      int j = vjs[jj];
      float vv = vg[((size_t)(b * NB + j)) * HIDDEN + o];
      a0 = fmaf(sE[0 * HEADS + h][jj], vv, a0);
      a1 = fmaf(sE[1 * HEADS + h][jj], vv, a1);
    }
    part[half][0][o] = a0;
    part[half][1][o] = a1;
  }
  __syncthreads();
  if (t < HIDDEN) {
    int h = t >> 4;
    agg[(size_t)(b * NB + qid0) * HIDDEN + t] =
        (part[0][0][t] + part[1][0][t]) * invs[0][h];
    if (qn > 1)
      agg[(size_t)(b * NB + qid1) * HIDDEN + t] =
          (part[0][1][t] + part[1][1][t]) * invs[1][h];
  }
}

// -------- K5: out proj + residual + mask + LayerNorm, 8 nodes/block ------------
__global__ __launch_bounds__(256) void out_kernel(
    const float* __restrict__ agg, const float* __restrict__ nf,
    const int* __restrict__ mask, const float* __restrict__ Wo,
    const float* __restrict__ bo, const float* __restrict__ gamma,
    const float* __restrict__ beta, float* __restrict__ out) {
  int n0 = blockIdx.x * 8;
  int t = threadIdx.x;                  // 256 = NODE_DIM
  __shared__ float4 as4[8][32];
  {
    int n = t >> 5, e = t & 31;         // 256 = 8*32 exactly
    as4[n][e] = ((const float4*)(agg + (size_t)(n0 + n) * HIDDEN))[e];
  }
  __syncthreads();
  float bv = bo[t];
  float acc[8] = {bv, bv, bv, bv, bv, bv, bv, bv};
  for (int kg = 0; kg < 32; ++kg) {
    float w0 = Wo[(kg * 4 + 0) * NODE_DIM + t];
    float w1 = Wo[(kg * 4 + 1) * NODE_DIM + t];
    float w2 = Wo[(kg * 4 + 2) * NODE_DIM + t];
    float w3 = Wo[(kg * 4 + 3) * NODE_DIM + t];
#pragma unroll
    for (int n = 0; n < 8; ++n) {
      float4 a = as4[n][kg];
      acc[n] = fmaf(a.x, w0, fmaf(a.y, w1, fmaf(a.z, w2, fmaf(a.w, w3, acc[n]))));
    }
  }
  float gv = gamma[t], btv = beta[t];
  __shared__ float rs[8][4], rs2[8][4];
  float xv[8];
#pragma unroll
  for (int n = 0; n < 8; ++n) {
    float mi = (mask[n0 + n] != 0) ? 1.0f : 0.0f;
    float x = mi * (nf[(size_t)(n0 + n) * NODE_DIM + t] + acc[n]);
    xv[n] = x;
    float s = x, s2 = x * x;
    for (int off = 32; off; off >>= 1) {
      s += __shfl_down(s, off, 64);
      s2 += __shfl_down(s2, off, 64);
    }
    if ((t & 63) == 0) { rs[n][t >> 6] = s; rs2[n][t >> 6] = s2; }
  }
  __syncthreads();
#pragma unroll
  for (int n = 0; n < 8; ++n) {
    float s  = rs[n][0] + rs[n][1] + rs[n][2] + rs[n][3];
    float s2 = rs2[n][0] + rs2[n][1] + rs2[n][2] + rs2[n][3];
    float mu = s * (1.0f / NODE_DIM);
    float var = fmaxf(s2 * (1.0f / NODE_DIM) - mu * mu, 0.0f);
    out[(size_t)(n0 + n) * NODE_DIM + t] =
        (xv[n] - mu) * rsqrtf(var + 1e-5f) * gv + btv;
  }
}

extern "C" void kernel_launch(void* const* d_in, const int* in_sizes, int n_in,
                              void* d_out, int out_size, void* d_ws, size_t ws_size,
                              hipStream_t stream) {
  const float* nf    = (const float*)d_in[0];
  const float* pos   = (const float*)d_in[1];
  const int*   mask  = (const int*)  d_in[2];
  const float* Wq    = (const float*)d_in[3];
  const float* Wk    = (const float*)d_in[4];
  const float* Wv    = (const float*)d_in[5];
  const float* W1    = (const float*)d_in[6];
  const float* b1    = (const float*)d_in[7];
  const float* W2    = (const float*)d_in[8];
  const float* b2    = (const float*)d_in[9];
  const float* Wo    = (const float*)d_in[10];
  const float* bo    = (const float*)d_in[11];
  const float* gamma = (const float*)d_in[12];
  const float* beta  = (const float*)d_in[13];

  const int QKV = NNODES * HIDDEN;      // 196608

  float* ws  = (float*)d_ws;
  float* q   = ws;
  float* k   = q + QKV;
  float* v   = k + QKV;
  float* agg = v + QKV;
  float* P   = agg + QKV;               // 2048
  float* b2m = P + HIDDEN * 16;         // 8
  float* pcx = b2m + 8;                 // 1536
  float* pcy = pcx + NNODES;            // 1536
  int*   vlist = (int*)(pcy + NNODES);  // 1536
  int*   cnt   = vlist + NNODES;        // 2

  qkv_kernel    <<<NNODES / 8, 256, 0, stream>>>(nf, Wq, Wk, Wv, mask, q, k, v, agg);
  prep_kernel   <<<1,          256, 0, stream>>>(W1, b1, W2, b2, P, b2m);
  compact_kernel<<<BATCH,      256, 0, stream>>>(mask, pos, vlist, cnt, pcx, pcy);
  attn_kernel   <<<NNODES / QT, 256, 0, stream>>>(pcx, pcy, vlist, cnt, P, b2m,
                                                  q, k, v, agg);
  out_kernel    <<<NNODES / 8, 256, 0, stream>>>(agg, nf, mask, Wo, bo, gamma,
                                                 beta, (float*)d_out);
}

// Round 6
// 214.650 us; speedup vs baseline: 1.9641x; 1.0632x over previous
//
#include <hip/hip_runtime.h>
#include <float.h>
#include <math.h>

#define NODE_DIM 256
#define HIDDEN   128
#define HEADS    8
#define HEAD_DIM 16
#define NB       768
#define BATCH    2
#define NNODES   (BATCH * NB)
#define SEP      776          // sE fp16 row stride: 776/2=388 words, 388%32=4

typedef _Float16 f16;

__device__ __forceinline__ float gelu_t(float u) {
  float u2 = u * u;
  float tt = u * fmaf(u2, 0.0356774081f, 0.7978845608f);
  return u / (1.0f + __expf(-2.0f * tt));
}

// ---- K1: per-batch mask compaction: cidx, compacted positions, zero-row ------
__global__ __launch_bounds__(256) void compact_kernel(
    const int* __restrict__ mask, const float* __restrict__ pos,
    int* __restrict__ cnt, int* __restrict__ cidx,
    float* __restrict__ pcx, float* __restrict__ pcy,
    float* __restrict__ aggc) {
  int b = blockIdx.x, t = threadIdx.x;
  __shared__ int cs;
  __shared__ int lst[NB];
  if (t == 0) cs = 0;
  __syncthreads();
  for (int j = t; j < NB; j += 256)
    if (mask[b * NB + j] != 0) { int p = atomicAdd(&cs, 1); lst[p] = j; }
  __syncthreads();
  int nv = cs;
  if (t == 0) cnt[b] = nv;
  for (int idx = t; idx < nv; idx += 256) {
    int j = lst[idx];
    cidx[b * NB + j] = idx;
    pcx[b * NB + idx] = pos[(b * NB + j) * 2];
    pcy[b * NB + idx] = pos[(b * NB + j) * 2 + 1];
  }
  if (b == 0 && t < HIDDEN) aggc[(size_t)NNODES * HIDDEN + t] = 0.0f;  // zero row
}

// ---- K2: pack P[c][12] = {W1x,W1y,W1d,b1, W2m[0..7]} + b2m -------------------
__global__ __launch_bounds__(256) void prep_kernel(
    const float* __restrict__ W1, const float* __restrict__ b1,
    const float* __restrict__ W2, const float* __restrict__ b2,
    float* __restrict__ P, float* __restrict__ b2m) {
  int t = threadIdx.x;
  __shared__ float w2s[HIDDEN * HEADS];
  for (int idx = t; idx < HIDDEN * HEADS; idx += 256) {
    int c = idx >> 3, h = idx & 7;
    float s = 0.0f;
    for (int d = 0; d < HEAD_DIM; ++d) s += W2[c * HIDDEN + h * HEAD_DIM + d];
    w2s[c * HEADS + h] = s * (1.0f / 16.0f);
  }
  if (t < HEADS) {
    float s = 0.0f;
    for (int d = 0; d < HEAD_DIM; ++d) s += b2[t * HEAD_DIM + d];
    b2m[t] = s * (1.0f / 16.0f);
  }
  __syncthreads();
  if (t < HIDDEN) {
    float* Pr = P + t * 12;
    Pr[0] = W1[0 * HIDDEN + t];
    Pr[1] = W1[1 * HIDDEN + t];
    Pr[2] = W1[2 * HIDDEN + t];
    Pr[3] = b1[t];
#pragma unroll
    for (int h = 0; h < HEADS; ++h) Pr[4 + h] = w2s[t * HEADS + h];
  }
}

// ---- K3: QKV projection, 8 nodes/block; writes compacted qc, kTc, vc ---------
__global__ __launch_bounds__(256) void qkv_kernel(
    const float* __restrict__ nf, const float* __restrict__ Wq,
    const float* __restrict__ Wk, const float* __restrict__ Wv,
    const int* __restrict__ mask, const int* __restrict__ cidx,
    float* __restrict__ qc, float* __restrict__ kTc, float* __restrict__ vc) {
  int n0 = blockIdx.x * 8;
  int t = threadIdx.x;
  int idx = t + (t >> 7 == 0 ? 0 : 0);
  (void)idx;
  for (int id = t; id < 3 * HIDDEN; id += 256) {
    int m = id >> 7, c = id & 127;
    const float* W = (m == 0) ? Wq : (m == 1) ? Wk : Wv;
    float acc[8] = {0.f, 0.f, 0.f, 0.f, 0.f, 0.f, 0.f, 0.f};
    for (int kk = 0; kk < NODE_DIM; ++kk) {
      float w = W[kk * HIDDEN + c];                 // coalesced vector load
#pragma unroll
      for (int n = 0; n < 8; ++n)                    // uniform -> s_load
        acc[n] = fmaf(nf[(size_t)(n0 + n) * NODE_DIM + kk], w, acc[n]);
    }
#pragma unroll
    for (int n = 0; n < 8; ++n) {
      int node = n0 + n;
      if (mask[node] != 0) {
        int b = node / NB;
        int ci = cidx[node];
        int slot = b * NB + ci;
        if (m == 0)       qc[(size_t)slot * HIDDEN + c] = acc[n];
        else if (m == 1)  kTc[((size_t)b * HIDDEN + c) * NB + ci] = acc[n];
        else              vc[(size_t)slot * HIDDEN + c] = acc[n];
      }
    }
  }
}

// ---- K4: fused edge-bias + attention, 1 valid query per 128-thread block -----
__global__ __launch_bounds__(128) void attn_kernel(
    const float* __restrict__ pcx, const float* __restrict__ pcy,
    const int* __restrict__ cnt, const float* __restrict__ P,
    const float* __restrict__ b2m, const float* __restrict__ qc,
    const float* __restrict__ kTc, const float* __restrict__ vc,
    float* __restrict__ aggc) {
  int x = blockIdx.x;
  int b = x & 1, ci = x >> 1;
  int nv = cnt[b];
  if (ci >= nv) return;
  int t = threadIdx.x;
  int slot = b * NB + ci;

  __shared__ f16  sE[HEADS][SEP];      // 12.4 KB
  __shared__ float qs[HIDDEN];
  __shared__ float invs[HEADS];

  qs[t] = qc[(size_t)slot * HIDDEN + t];
  float pix = pcx[slot], piy = pcy[slot];
  __syncthreads();

  // ---- phase A: qk dots (h = t>>4, 16 jj-lanes), kTc coalesced over jj ----
  {
    int h = t >> 4, l = t & 15;
    const float* kb = kTc + ((size_t)b * HIDDEN + h * 16) * NB;
    float4 qa0 = ((const float4*)(qs + h * 16))[0];
    float4 qa1 = ((const float4*)(qs + h * 16))[1];
    float4 qa2 = ((const float4*)(qs + h * 16))[2];
    float4 qa3 = ((const float4*)(qs + h * 16))[3];
    float bh = b2m[h];
    for (int jj = l; jj < nv; jj += 16) {
      float d =
        qa0.x*kb[0*NB+jj] + qa0.y*kb[1*NB+jj] + qa0.z*kb[2*NB+jj] + qa0.w*kb[3*NB+jj] +
        qa1.x*kb[4*NB+jj] + qa1.y*kb[5*NB+jj] + qa1.z*kb[6*NB+jj] + qa1.w*kb[7*NB+jj] +
        qa2.x*kb[8*NB+jj] + qa2.y*kb[9*NB+jj] + qa2.z*kb[10*NB+jj] + qa2.w*kb[11*NB+jj] +
        qa3.x*kb[12*NB+jj] + qa3.y*kb[13*NB+jj] + qa3.z*kb[14*NB+jj] + qa3.w*kb[15*NB+jj];
      sE[h][jj] = (f16)fmaf(d, 0.25f, bh);
    }
  }
  __syncthreads();

  // ---- phase B: edge-MLP bias, 3 keys per thread, P via uniform s_load ----
  for (int base = 0; base < nv; base += 3 * 128) {
    int k0 = base + t, k1 = base + t + 128, k2 = base + t + 256;
    bool v0 = k0 < nv, v1 = k1 < nv, v2 = k2 < nv;
    int c0 = v0 ? k0 : 0, c1 = v1 ? k1 : 0, c2 = v2 ? k2 : 0;
    float ux0, uy0, dd0, ux1, uy1, dd1, ux2, uy2, dd2;
    {
      float dx = pix - pcx[b * NB + c0], dy = piy - pcy[b * NB + c0];
      float sq = dx * dx + dy * dy;
      dd0 = sqrtf(sq + 1e-6f);
      float dn = fmaxf(sqrtf(sq), 1e-6f);
      ux0 = dx / dn; uy0 = dy / dn;
    }
    {
      float dx = pix - pcx[b * NB + c1], dy = piy - pcy[b * NB + c1];
      float sq = dx * dx + dy * dy;
      dd1 = sqrtf(sq + 1e-6f);
      float dn = fmaxf(sqrtf(sq), 1e-6f);
      ux1 = dx / dn; uy1 = dy / dn;
    }
    {
      float dx = pix - pcx[b * NB + c2], dy = piy - pcy[b * NB + c2];
      float sq = dx * dx + dy * dy;
      dd2 = sqrtf(sq + 1e-6f);
      float dn = fmaxf(sqrtf(sq), 1e-6f);
      ux2 = dx / dn; uy2 = dy / dn;
    }
    float bias0[8] = {}, bias1[8] = {}, bias2[8] = {};
#pragma unroll 4
    for (int c = 0; c < HIDDEN; ++c) {
      const float4* Pc = (const float4*)(P + c * 12);   // uniform -> s_load_x4
      float4 p0 = Pc[0], p1 = Pc[1], p2 = Pc[2];
      float u0 = fmaf(ux0, p0.x, fmaf(uy0, p0.y, fmaf(dd0, p0.z, p0.w)));
      float g0 = gelu_t(u0);
      float u1 = fmaf(ux1, p0.x, fmaf(uy1, p0.y, fmaf(dd1, p0.z, p0.w)));
      float g1 = gelu_t(u1);
      float u2 = fmaf(ux2, p0.x, fmaf(uy2, p0.y, fmaf(dd2, p0.z, p0.w)));
      float g2 = gelu_t(u2);
      bias0[0] = fmaf(g0, p1.x, bias0[0]); bias1[0] = fmaf(g1, p1.x, bias1[0]); bias2[0] = fmaf(g2, p1.x, bias2[0]);
      bias0[1] = fmaf(g0, p1.y, bias0[1]); bias1[1] = fmaf(g1, p1.y, bias1[1]); bias2[1] = fmaf(g2, p1.y, bias2[1]);
      bias0[2] = fmaf(g0, p1.z, bias0[2]); bias1[2] = fmaf(g1, p1.z, bias1[2]); bias2[2] = fmaf(g2, p1.z, bias2[2]);
      bias0[3] = fmaf(g0, p1.w, bias0[3]); bias1[3] = fmaf(g1, p1.w, bias1[3]); bias2[3] = fmaf(g2, p1.w, bias2[3]);
      bias0[4] = fmaf(g0, p2.x, bias0[4]); bias1[4] = fmaf(g1, p2.x, bias1[4]); bias2[4] = fmaf(g2, p2.x, bias2[4]);
      bias0[5] = fmaf(g0, p2.y, bias0[5]); bias1[5] = fmaf(g1, p2.y, bias1[5]); bias2[5] = fmaf(g2, p2.y, bias2[5]);
      bias0[6] = fmaf(g0, p2.z, bias0[6]); bias1[6] = fmaf(g1, p2.z, bias1[6]); bias2[6] = fmaf(g2, p2.z, bias2[6]);
      bias0[7] = fmaf(g0, p2.w, bias0[7]); bias1[7] = fmaf(g1, p2.w, bias1[7]); bias2[7] = fmaf(g2, p2.w, bias2[7]);
    }
    if (v0) {
#pragma unroll
      for (int h = 0; h < 8; ++h) sE[h][k0] = (f16)((float)sE[h][k0] + bias0[h]);
    }
    if (v1) {
#pragma unroll
      for (int h = 0; h < 8; ++h) sE[h][k1] = (f16)((float)sE[h][k1] + bias1[h]);
    }
    if (v2) {
#pragma unroll
      for (int h = 0; h < 8; ++h) sE[h][k2] = (f16)((float)sE[h][k2] + bias2[h]);
    }
  }
  __syncthreads();

  // ---- phase C: softmax per head (8 groups of 16 lanes) ----
  {
    int h = t >> 4, l = t & 15;
    float m = -FLT_MAX;
    for (int jj = l; jj < nv; jj += 16) m = fmaxf(m, (float)sE[h][jj]);
    for (int off = 8; off; off >>= 1) m = fmaxf(m, __shfl_down(m, off, 16));
    m = __shfl(m, 0, 16);
    float s = 0.0f;
    for (int jj = l; jj < nv; jj += 16) {
      float e = __expf((float)sE[h][jj] - m);
      sE[h][jj] = (f16)e;
      s += e;
    }
    for (int off = 8; off; off >>= 1) s += __shfl_down(s, off, 16);
    if (l == 0) invs[h] = 1.0f / s;
  }
  __syncthreads();

  // ---- phase D: agg[o] = invs[h] * sum_jj w * vc[jj][o] ----
  {
    int h = t >> 4;
    float acc = 0.0f;
#pragma unroll 4
    for (int jj = 0; jj < nv; ++jj)
      acc = fmaf((float)sE[h][jj], vc[((size_t)(b * NB + jj)) * HIDDEN + t], acc);
    aggc[(size_t)slot * HIDDEN + t] = acc * invs[h];
  }
}

// ---- K5: out proj + residual + mask + LayerNorm, 8 nodes/block ---------------
__global__ __launch_bounds__(256) void out_kernel(
    const float* __restrict__ aggc, const float* __restrict__ nf,
    const int* __restrict__ mask, const int* __restrict__ cidx,
    const float* __restrict__ Wo, const float* __restrict__ bo,
    const float* __restrict__ gamma, const float* __restrict__ beta,
    float* __restrict__ out) {
  int n0 = blockIdx.x * 8;
  int t = threadIdx.x;                  // 256 = NODE_DIM
  int slot[8];
#pragma unroll
  for (int n = 0; n < 8; ++n) {
    int node = n0 + n;
    slot[n] = (mask[node] != 0) ? ((node / NB) * NB + cidx[node]) : NNODES;
  }
  float bv = bo[t];
  float acc[8] = {bv, bv, bv, bv, bv, bv, bv, bv};
  for (int kk = 0; kk < HIDDEN; ++kk) {
    float w = Wo[kk * NODE_DIM + t];    // coalesced
#pragma unroll
    for (int n = 0; n < 8; ++n)          // uniform -> s_load
      acc[n] = fmaf(aggc[(size_t)slot[n] * HIDDEN + kk], w, acc[n]);
  }
  float gv = gamma[t], btv = beta[t];
  __shared__ float rs[8][4], rs2[8][4];
  float xv[8];
#pragma unroll
  for (int n = 0; n < 8; ++n) {
    float mi = (mask[n0 + n] != 0) ? 1.0f : 0.0f;
    float x = mi * (nf[(size_t)(n0 + n) * NODE_DIM + t] + acc[n]);
    xv[n] = x;
    float s = x, s2 = x * x;
    for (int off = 32; off; off >>= 1) {
      s += __shfl_down(s, off, 64);
      s2 += __shfl_down(s2, off, 64);
    }
    if ((t & 63) == 0) { rs[n][t >> 6] = s; rs2[n][t >> 6] = s2; }
  }
  __syncthreads();
#pragma unroll
  for (int n = 0; n < 8; ++n) {
    float s  = rs[n][0] + rs[n][1] + rs[n][2] + rs[n][3];
    float s2 = rs2[n][0] + rs2[n][1] + rs2[n][2] + rs2[n][3];
    float mu = s * (1.0f / NODE_DIM);
    float var = fmaxf(s2 * (1.0f / NODE_DIM) - mu * mu, 0.0f);
    out[(size_t)(n0 + n) * NODE_DIM + t] =
        (xv[n] - mu) * rsqrtf(var + 1e-5f) * gv + btv;
  }
}

extern "C" void kernel_launch(void* const* d_in, const int* in_sizes, int n_in,
                              void* d_out, int out_size, void* d_ws, size_t ws_size,
                              hipStream_t stream) {
  const float* nf    = (const float*)d_in[0];
  const float* pos   = (const float*)d_in[1];
  const int*   mask  = (const int*)  d_in[2];
  const float* Wq    = (const float*)d_in[3];
  const float* Wk    = (const float*)d_in[4];
  const float* Wv    = (const float*)d_in[5];
  const float* W1    = (const float*)d_in[6];
  const float* b1    = (const float*)d_in[7];
  const float* W2    = (const float*)d_in[8];
  const float* b2    = (const float*)d_in[9];
  const float* Wo    = (const float*)d_in[10];
  const float* bo    = (const float*)d_in[11];
  const float* gamma = (const float*)d_in[12];
  const float* beta  = (const float*)d_in[13];

  const int QKV = NNODES * HIDDEN;      // 196608

  float* ws   = (float*)d_ws;
  float* qc   = ws;
  float* kTc  = qc + QKV;
  float* vc   = kTc + QKV;
  float* aggc = vc + QKV;                     // (NNODES+1) rows
  float* P    = aggc + (NNODES + 1) * HIDDEN; // 1536
  float* b2m  = P + HIDDEN * 12;              // 8
  float* pcx  = b2m + 8;                      // 1536
  float* pcy  = pcx + NNODES;                 // 1536
  int*   cidx = (int*)(pcy + NNODES);         // 1536
  int*   cnt  = cidx + NNODES;                // 2

  compact_kernel<<<BATCH,      256, 0, stream>>>(mask, pos, cnt, cidx, pcx, pcy, aggc);
  prep_kernel   <<<1,          256, 0, stream>>>(W1, b1, W2, b2, P, b2m);
  qkv_kernel    <<<NNODES / 8, 256, 0, stream>>>(nf, Wq, Wk, Wv, mask, cidx,
                                                 qc, kTc, vc);
  attn_kernel   <<<2 * NB,     128, 0, stream>>>(pcx, pcy, cnt, P, b2m,
                                                 qc, kTc, vc, aggc);
  out_kernel    <<<NNODES / 8, 256, 0, stream>>>(aggc, nf, mask, cidx, Wo, bo,
                                                 gamma, beta, (float*)d_out);
}

// Round 7
// 178.937 us; speedup vs baseline: 2.3561x; 1.1996x over previous
//
#include <hip/hip_runtime.h>
#include <float.h>
#include <math.h>

#define NODE_DIM 256
#define HIDDEN   128
#define HEADS    8
#define HEAD_DIM 16
#define NB       768
#define BATCH    2
#define NNODES   (BATCH * NB)
#define SEP      776          // f16 row stride: 776*2B = 388 words, 388%32=4

typedef _Float16 f16;

// tanh-GELU with folded constants: g = u / (1 + exp(u*(c1 + c3*u^2)))
// c1 = -2*0.7978845608, c3 = -2*0.7978845608*0.044715
__device__ __forceinline__ float gelu_f(float u) {
  float u2 = u * u;
  float m  = u * fmaf(u2, -0.0713548162f, -1.5957691216f);
  float e  = __expf(m);                       // v_mul + v_exp_f32
  return u * __builtin_amdgcn_rcpf(1.0f + e); // v_add + v_rcp_f32 + v_mul
}

// ---- K1: setup. blocks 0,1: per-batch compaction; block 2: pack P + b2m ------
__global__ __launch_bounds__(256) void setup_kernel(
    const int* __restrict__ mask, const float* __restrict__ pos,
    const float* __restrict__ W1, const float* __restrict__ b1,
    const float* __restrict__ W2, const float* __restrict__ b2,
    int* __restrict__ cnt, int* __restrict__ cidx, int* __restrict__ vlist,
    int* __restrict__ mlist, float* __restrict__ pcx, float* __restrict__ pcy,
    float* __restrict__ P, float* __restrict__ b2m) {
  int blk = blockIdx.x, t = threadIdx.x;
  if (blk < 2) {
    int b = blk;
    __shared__ int cs, ms;
    __shared__ int lst[NB], mlst[NB];
    if (t == 0) { cs = 0; ms = 0; }
    __syncthreads();
    for (int j = t; j < NB; j += 256) {
      if (mask[b * NB + j] != 0) { int p = atomicAdd(&cs, 1); lst[p] = j; }
      else                       { int p = atomicAdd(&ms, 1); mlst[p] = j; }
    }
    __syncthreads();
    int nv = cs;
    if (t == 0) cnt[b] = nv;
    for (int i = t; i < nv; i += 256) {
      int j = lst[i];
      cidx[b * NB + j] = i;
      vlist[b * NB + i] = j;
      pcx[b * NB + i] = pos[(b * NB + j) * 2];
      pcy[b * NB + i] = pos[(b * NB + j) * 2 + 1];
    }
    for (int i = t; i < NB - nv; i += 256) mlist[b * NB + i] = mlst[i];
  } else {
    __shared__ float w2s[HIDDEN * HEADS];
    for (int idx = t; idx < HIDDEN * HEADS; idx += 256) {
      int c = idx >> 3, h = idx & 7;
      float s = 0.0f;
      for (int d = 0; d < HEAD_DIM; ++d) s += W2[c * HIDDEN + h * HEAD_DIM + d];
      w2s[idx] = s * (1.0f / 16.0f);
    }
    if (t < HEADS) {
      float s = 0.0f;
      for (int d = 0; d < HEAD_DIM; ++d) s += b2[t * HEAD_DIM + d];
      b2m[t] = s * (1.0f / 16.0f);
    }
    __syncthreads();
    if (t < HIDDEN) {
      float* Pr = P + t * 12;
      Pr[0] = W1[t];
      Pr[1] = W1[HIDDEN + t];
      Pr[2] = W1[2 * HIDDEN + t];
      Pr[3] = b1[t];
#pragma unroll
      for (int h = 0; h < HEADS; ++h) Pr[4 + h] = w2s[t * 8 + h];
    }
  }
}

// ---- K2: QKV projection, 4 nodes/block, compacted writes ---------------------
__global__ __launch_bounds__(256) void qkv_kernel(
    const float* __restrict__ nf, const float* __restrict__ Wq,
    const float* __restrict__ Wk, const float* __restrict__ Wv,
    const int* __restrict__ mask, const int* __restrict__ cidx,
    float* __restrict__ qc, float* __restrict__ kTc, float* __restrict__ vc) {
  int n0 = blockIdx.x * 4;
  int t = threadIdx.x;
  for (int id = t; id < 3 * HIDDEN; id += 256) {
    int m = id >> 7, c = id & 127;
    const float* W = (m == 0) ? Wq : (m == 1) ? Wk : Wv;
    const float* x0 = nf + (size_t)(n0 + 0) * NODE_DIM;
    const float* x1 = nf + (size_t)(n0 + 1) * NODE_DIM;
    const float* x2 = nf + (size_t)(n0 + 2) * NODE_DIM;
    const float* x3 = nf + (size_t)(n0 + 3) * NODE_DIM;
    float a0 = 0.f, a1 = 0.f, a2 = 0.f, a3 = 0.f;
#pragma unroll 8
    for (int kk = 0; kk < NODE_DIM; ++kk) {
      float w = W[kk * HIDDEN + c];      // coalesced
      a0 = fmaf(x0[kk], w, a0);          // uniform -> s_load
      a1 = fmaf(x1[kk], w, a1);
      a2 = fmaf(x2[kk], w, a2);
      a3 = fmaf(x3[kk], w, a3);
    }
    float acc[4] = {a0, a1, a2, a3};
#pragma unroll
    for (int n = 0; n < 4; ++n) {
      int node = n0 + n;
      if (mask[node] != 0) {
        int b = node / NB;
        int ci = cidx[node];
        int slot = b * NB + ci;
        if (m == 0)      qc[(size_t)slot * HIDDEN + c] = acc[n];
        else if (m == 1) kTc[((size_t)b * HIDDEN + c) * NB + ci] = acc[n];
        else             vc[(size_t)slot * HIDDEN + c] = acc[n];
      }
    }
  }
}

// ---- K3: fused edge-bias + attention + out-proj + LayerNorm ------------------
__global__ __launch_bounds__(256) void attn_kernel(
    const float* __restrict__ pcx, const float* __restrict__ pcy,
    const int* __restrict__ cnt, const int* __restrict__ vlist,
    const int* __restrict__ mlist, const float* __restrict__ P,
    const float* __restrict__ b2m, const float* __restrict__ qc,
    const float* __restrict__ kTc, const float* __restrict__ vc,
    const float* __restrict__ nf, const float* __restrict__ Wo,
    const float* __restrict__ bo, const float* __restrict__ gamma,
    const float* __restrict__ beta, float* __restrict__ out) {
  int x = blockIdx.x;
  int b = x & 1, ci = x >> 1;
  int nv = cnt[b];
  int t = threadIdx.x;

  if (ci >= nv) {                       // masked node -> x==0 -> LN gives beta
    int node = b * NB + mlist[b * NB + (ci - nv)];
    out[(size_t)node * NODE_DIM + t] = beta[t];
    return;
  }
  int node = b * NB + vlist[b * NB + ci];
  int slot = b * NB + ci;

  __shared__ f16  sE[HEADS][SEP];       // 12.4 KB
  __shared__ __align__(16) float qs[HIDDEN];
  __shared__ float invs[HEADS];
  __shared__ float part[2][HIDDEN];
  __shared__ __align__(16) float aggL[HIDDEN];
  __shared__ float red[2][4];

  if (t < HIDDEN) qs[t] = qc[(size_t)slot * HIDDEN + t];
  float pix = pcx[slot], piy = pcy[slot];
  __syncthreads();

  // ---- A: qk dots (8 heads x 32 lanes), kTc coalesced over jj ----
  {
    int h = t >> 5, l = t & 31;
    const float* kb = kTc + ((size_t)b * HIDDEN + h * 16) * NB;
    float4 qa0 = ((const float4*)(qs + h * 16))[0];
    float4 qa1 = ((const float4*)(qs + h * 16))[1];
    float4 qa2 = ((const float4*)(qs + h * 16))[2];
    float4 qa3 = ((const float4*)(qs + h * 16))[3];
    float bh = b2m[h];
    for (int jj = l; jj < nv; jj += 32) {
      float d =
        qa0.x*kb[0*NB+jj] + qa0.y*kb[1*NB+jj] + qa0.z*kb[2*NB+jj] + qa0.w*kb[3*NB+jj] +
        qa1.x*kb[4*NB+jj] + qa1.y*kb[5*NB+jj] + qa1.z*kb[6*NB+jj] + qa1.w*kb[7*NB+jj] +
        qa2.x*kb[8*NB+jj] + qa2.y*kb[9*NB+jj] + qa2.z*kb[10*NB+jj] + qa2.w*kb[11*NB+jj] +
        qa3.x*kb[12*NB+jj] + qa3.y*kb[13*NB+jj] + qa3.z*kb[14*NB+jj] + qa3.w*kb[15*NB+jj];
      sE[h][jj] = (f16)fmaf(d, 0.25f, bh);
    }
  }
  __syncthreads();

  // ---- B: edge-MLP bias; 128 key-lanes x 2 c-halves, 3 key-slots/thread ----
  {
    int kk = t & 127, ch = t >> 7;
    int cb = ch * 64;
    for (int base = 0; base < nv; base += 384) {
      int k0 = base + kk, k1 = k0 + 128, k2 = k0 + 256;
      bool v0 = k0 < nv, v1 = k1 < nv, v2 = k2 < nv;
      int s0 = b * NB + (v0 ? k0 : 0);
      int s1 = b * NB + (v1 ? k1 : 0);
      int s2 = b * NB + (v2 ? k2 : 0);
      float ux0, uy0, dd0, ux1, uy1, dd1, ux2, uy2, dd2;
      {
        float dx = pix - pcx[s0], dy = piy - pcy[s0];
        float sq = dx * dx + dy * dy;
        dd0 = sqrtf(sq + 1e-6f);
        float dn = fmaxf(sqrtf(sq), 1e-6f);
        ux0 = dx / dn; uy0 = dy / dn;
      }
      {
        float dx = pix - pcx[s1], dy = piy - pcy[s1];
        float sq = dx * dx + dy * dy;
        dd1 = sqrtf(sq + 1e-6f);
        float dn = fmaxf(sqrtf(sq), 1e-6f);
        ux1 = dx / dn; uy1 = dy / dn;
      }
      {
        float dx = pix - pcx[s2], dy = piy - pcy[s2];
        float sq = dx * dx + dy * dy;
        dd2 = sqrtf(sq + 1e-6f);
        float dn = fmaxf(sqrtf(sq), 1e-6f);
        ux2 = dx / dn; uy2 = dy / dn;
      }
      float bias0[8] = {}, bias1[8] = {}, bias2[8] = {};
#pragma unroll 4
      for (int c = cb; c < cb + 64; ++c) {
        const float4* Pc = (const float4*)(P + c * 12);  // uniform -> s_load_x4
        float4 p0 = Pc[0], p1 = Pc[1], p2 = Pc[2];
        float g0 = gelu_f(fmaf(ux0, p0.x, fmaf(uy0, p0.y, fmaf(dd0, p0.z, p0.w))));
        float g1 = gelu_f(fmaf(ux1, p0.x, fmaf(uy1, p0.y, fmaf(dd1, p0.z, p0.w))));
        float g2 = gelu_f(fmaf(ux2, p0.x, fmaf(uy2, p0.y, fmaf(dd2, p0.z, p0.w))));
        bias0[0]=fmaf(g0,p1.x,bias0[0]); bias1[0]=fmaf(g1,p1.x,bias1[0]); bias2[0]=fmaf(g2,p1.x,bias2[0]);
        bias0[1]=fmaf(g0,p1.y,bias0[1]); bias1[1]=fmaf(g1,p1.y,bias1[1]); bias2[1]=fmaf(g2,p1.y,bias2[1]);
        bias0[2]=fmaf(g0,p1.z,bias0[2]); bias1[2]=fmaf(g1,p1.z,bias1[2]); bias2[2]=fmaf(g2,p1.z,bias2[2]);
        bias0[3]=fmaf(g0,p1.w,bias0[3]); bias1[3]=fmaf(g1,p1.w,bias1[3]); bias2[3]=fmaf(g2,p1.w,bias2[3]);
        bias0[4]=fmaf(g0,p2.x,bias0[4]); bias1[4]=fmaf(g1,p2.x,bias1[4]); bias2[4]=fmaf(g2,p2.x,bias2[4]);
        bias0[5]=fmaf(g0,p2.y,bias0[5]); bias1[5]=fmaf(g1,p2.y,bias1[5]); bias2[5]=fmaf(g2,p2.y,bias2[5]);
        bias0[6]=fmaf(g0,p2.z,bias0[6]); bias1[6]=fmaf(g1,p2.z,bias1[6]); bias2[6]=fmaf(g2,p2.z,bias2[6]);
        bias0[7]=fmaf(g0,p2.w,bias0[7]); bias1[7]=fmaf(g1,p2.w,bias1[7]); bias2[7]=fmaf(g2,p2.w,bias2[7]);
      }
      // two rounds so the c-halves don't race on the f16 RMW
      for (int r = 0; r < 2; ++r) {
        if (ch == r) {
          if (v0) {
#pragma unroll
            for (int h = 0; h < 8; ++h) sE[h][k0] = (f16)((float)sE[h][k0] + bias0[h]);
          }
          if (v1) {
#pragma unroll
            for (int h = 0; h < 8; ++h) sE[h][k1] = (f16)((float)sE[h][k1] + bias1[h]);
          }
          if (v2) {
#pragma unroll
            for (int h = 0; h < 8; ++h) sE[h][k2] = (f16)((float)sE[h][k2] + bias2[h]);
          }
        }
        __syncthreads();
      }
    }
  }

  // ---- C: softmax per head (8 groups x 32 lanes) ----
  {
    int h = t >> 5, l = t & 31;
    float m = -FLT_MAX;
    for (int jj = l; jj < nv; jj += 32) m = fmaxf(m, (float)sE[h][jj]);
    for (int off = 16; off; off >>= 1) m = fmaxf(m, __shfl_down(m, off, 32));
    m = __shfl(m, 0, 32);
    float s = 0.0f;
    for (int jj = l; jj < nv; jj += 32) {
      float e = __expf((float)sE[h][jj] - m);
      sE[h][jj] = (f16)e;
      s += e;
    }
    for (int off = 16; off; off >>= 1) s += __shfl_down(s, off, 32);
    if (l == 0) invs[h] = 1.0f / s;
  }
  __syncthreads();

  // ---- D: weighted V accumulation -> aggL in LDS ----
  {
    int o = t & 127, half = t >> 7, h = o >> 4;
    float acc = 0.0f;
    for (int jj = half; jj < nv; jj += 2)
      acc = fmaf((float)sE[h][jj], vc[((size_t)(b * NB + jj)) * HIDDEN + o], acc);
    part[half][o] = acc;
  }
  __syncthreads();
  if (t < HIDDEN) aggL[t] = (part[0][t] + part[1][t]) * invs[t >> 4];
  __syncthreads();

  // ---- E: out projection + residual + LayerNorm ----
  {
    float y = bo[t];
    const float4* a4 = (const float4*)aggL;
#pragma unroll 4
    for (int kg = 0; kg < 32; ++kg) {
      float4 a = a4[kg];                               // ds_read_b128 broadcast
      y = fmaf(a.x, Wo[(4 * kg + 0) * NODE_DIM + t],
          fmaf(a.y, Wo[(4 * kg + 1) * NODE_DIM + t],
          fmaf(a.z, Wo[(4 * kg + 2) * NODE_DIM + t],
          fmaf(a.w, Wo[(4 * kg + 3) * NODE_DIM + t], y))));
    }
    float xv = nf[(size_t)node * NODE_DIM + t] + y;
    float s = xv, s2 = xv * xv;
    for (int off = 32; off; off >>= 1) {
      s += __shfl_down(s, off, 64);
      s2 += __shfl_down(s2, off, 64);
    }
    if ((t & 63) == 0) { red[0][t >> 6] = s; red[1][t >> 6] = s2; }
    __syncthreads();
    s  = red[0][0] + red[0][1] + red[0][2] + red[0][3];
    s2 = red[1][0] + red[1][1] + red[1][2] + red[1][3];
    float mu = s * (1.0f / NODE_DIM);
    float var = fmaxf(s2 * (1.0f / NODE_DIM) - mu * mu, 0.0f);
    out[(size_t)node * NODE_DIM + t] =
        (xv - mu) * rsqrtf(var + 1e-5f) * gamma[t] + beta[t];
  }
}

extern "C" void kernel_launch(void* const* d_in, const int* in_sizes, int n_in,
                              void* d_out, int out_size, void* d_ws, size_t ws_size,
                              hipStream_t stream) {
  const float* nf    = (const float*)d_in[0];
  const float* pos   = (const float*)d_in[1];
  const int*   mask  = (const int*)  d_in[2];
  const float* Wq    = (const float*)d_in[3];
  const float* Wk    = (const float*)d_in[4];
  const float* Wv    = (const float*)d_in[5];
  const float* W1    = (const float*)d_in[6];
  const float* b1    = (const float*)d_in[7];
  const float* W2    = (const float*)d_in[8];
  const float* b2    = (const float*)d_in[9];
  const float* Wo    = (const float*)d_in[10];
  const float* bo    = (const float*)d_in[11];
  const float* gamma = (const float*)d_in[12];
  const float* beta  = (const float*)d_in[13];

  const int QKV = NNODES * HIDDEN;            // 196608

  float* ws   = (float*)d_ws;
  float* qc   = ws;
  float* kTc  = qc + QKV;
  float* vc   = kTc + QKV;
  float* P    = vc + QKV;                     // 1536
  float* b2m  = P + HIDDEN * 12;              // 8
  float* pcx  = b2m + 8;                      // 1536
  float* pcy  = pcx + NNODES;                 // 1536
  int*   cidx = (int*)(pcy + NNODES);         // 1536
  int*   vlist= cidx + NNODES;                // 1536
  int*   mlist= vlist + NNODES;               // 1536
  int*   cnt  = mlist + NNODES;               // 2

  setup_kernel<<<3,          256, 0, stream>>>(mask, pos, W1, b1, W2, b2,
                                               cnt, cidx, vlist, mlist,
                                               pcx, pcy, P, b2m);
  qkv_kernel  <<<NNODES / 4, 256, 0, stream>>>(nf, Wq, Wk, Wv, mask, cidx,
                                               qc, kTc, vc);
  attn_kernel <<<2 * NB,     256, 0, stream>>>(pcx, pcy, cnt, vlist, mlist,
                                               P, b2m, qc, kTc, vc,
                                               nf, Wo, bo, gamma, beta,
                                               (float*)d_out);
}

// Round 8
// 140.769 us; speedup vs baseline: 2.9949x; 1.2711x over previous
//
#include <hip/hip_runtime.h>
#include <float.h>
#include <math.h>

#define NODE_DIM 256
#define HIDDEN   128
#define HEADS    8
#define HEAD_DIM 16
#define NB       768
#define BATCH    2
#define NNODES   (BATCH * NB)
#define SEP      776          // f16 row stride: 776*2B = 388 words, 388%32=4

typedef _Float16 f16;

// tanh-GELU with folded constants: g = u / (1 + exp(u*(c1 + c3*u^2)))
__device__ __forceinline__ float gelu_f(float u) {
  float u2 = u * u;
  float m  = u * fmaf(u2, -0.0713548162f, -1.5957691216f);
  float e  = __expf(m);
  return u * __builtin_amdgcn_rcpf(1.0f + e);
}

// ---- K1: setup. blocks 0,1: per-batch compaction (+kTc pad); block 2: pack P -
__global__ __launch_bounds__(256) void setup_kernel(
    const int* __restrict__ mask, const float* __restrict__ pos,
    const float* __restrict__ W1, const float* __restrict__ b1,
    const float* __restrict__ W2, const float* __restrict__ b2,
    int* __restrict__ cnt, int* __restrict__ cidx, int* __restrict__ vlist,
    int* __restrict__ mlist, float* __restrict__ pcx, float* __restrict__ pcy,
    float* __restrict__ kTc, float* __restrict__ P, float* __restrict__ b2m) {
  int blk = blockIdx.x, t = threadIdx.x;
  if (blk < 2) {
    int b = blk;
    __shared__ int cs, ms;
    __shared__ int lst[NB], mlst[NB];
    if (t == 0) { cs = 0; ms = 0; }
    __syncthreads();
    for (int j = t; j < NB; j += 256) {
      if (mask[b * NB + j] != 0) { int p = atomicAdd(&cs, 1); lst[p] = j; }
      else                       { int p = atomicAdd(&ms, 1); mlst[p] = j; }
    }
    __syncthreads();
    int nv = cs;
    if (t == 0) cnt[b] = nv;
    for (int i = t; i < nv; i += 256) {
      int j = lst[i];
      cidx[b * NB + j] = i;
      vlist[b * NB + i] = j;
      pcx[b * NB + i] = pos[(b * NB + j) * 2];
      pcy[b * NB + i] = pos[(b * NB + j) * 2 + 1];
    }
    for (int i = t; i < NB - nv; i += 256) mlist[b * NB + i] = mlst[i];
    // zero-pad kTc columns [nv, nvp) so phase-A float4 reads are defined
    int nvp = (nv + 3) & ~3;
    if (nvp > nv && t < HIDDEN) {
      for (int col = nv; col < nvp; ++col)
        kTc[((size_t)b * HIDDEN + t) * NB + col] = 0.0f;
    }
  } else {
    __shared__ float w2s[HIDDEN * HEADS];
    for (int idx = t; idx < HIDDEN * HEADS; idx += 256) {
      int c = idx >> 3, h = idx & 7;
      float s = 0.0f;
      for (int d = 0; d < HEAD_DIM; ++d) s += W2[c * HIDDEN + h * HEAD_DIM + d];
      w2s[idx] = s * (1.0f / 16.0f);
    }
    if (t < HEADS) {
      float s = 0.0f;
      for (int d = 0; d < HEAD_DIM; ++d) s += b2[t * HEAD_DIM + d];
      b2m[t] = s * (1.0f / 16.0f);
    }
    __syncthreads();
    if (t < HIDDEN) {
      float* Pr = P + t * 12;
      Pr[0] = W1[t];
      Pr[1] = W1[HIDDEN + t];
      Pr[2] = W1[2 * HIDDEN + t];
      Pr[3] = b1[t];
#pragma unroll
      for (int h = 0; h < HEADS; ++h) Pr[4 + h] = w2s[t * 8 + h];
    }
  }
}

// ---- K2: QKV projection, 2 nodes/block, compacted writes ---------------------
__global__ __launch_bounds__(256) void qkv_kernel(
    const float* __restrict__ nf, const float* __restrict__ Wq,
    const float* __restrict__ Wk, const float* __restrict__ Wv,
    const int* __restrict__ mask, const int* __restrict__ cidx,
    float* __restrict__ qc, float* __restrict__ kTc, float* __restrict__ vc) {
  int n0 = blockIdx.x * 2;
  int t = threadIdx.x;
  const float* x0 = nf + (size_t)(n0 + 0) * NODE_DIM;
  const float* x1 = nf + (size_t)(n0 + 1) * NODE_DIM;
  for (int id = t; id < 3 * HIDDEN; id += 256) {
    int m = id >> 7, c = id & 127;
    const float* W = (m == 0) ? Wq : (m == 1) ? Wk : Wv;
    float a0 = 0.f, b0 = 0.f, a1 = 0.f, b1_ = 0.f;
#pragma unroll 8
    for (int kk = 0; kk < NODE_DIM; kk += 2) {
      float w0 = W[kk * HIDDEN + c];
      float w1 = W[(kk + 1) * HIDDEN + c];
      a0 = fmaf(x0[kk], w0, a0);  b0 = fmaf(x0[kk + 1], w1, b0);
      a1 = fmaf(x1[kk], w0, a1);  b1_ = fmaf(x1[kk + 1], w1, b1_);
    }
    float acc[2] = {a0 + b0, a1 + b1_};
#pragma unroll
    for (int n = 0; n < 2; ++n) {
      int node = n0 + n;
      if (mask[node] != 0) {
        int b = node / NB;
        int ci = cidx[node];
        int slot = b * NB + ci;
        if (m == 0)      qc[(size_t)slot * HIDDEN + c] = acc[n];
        else if (m == 1) kTc[((size_t)b * HIDDEN + c) * NB + ci] = acc[n];
        else             vc[(size_t)slot * HIDDEN + c] = acc[n];
      }
    }
  }
}

// ---- K3: fused edge-bias + attention + out-proj + LayerNorm ------------------
__global__ __launch_bounds__(256) void attn_kernel(
    const float* __restrict__ pcx, const float* __restrict__ pcy,
    const int* __restrict__ cnt, const int* __restrict__ vlist,
    const int* __restrict__ mlist, const float* __restrict__ P,
    const float* __restrict__ b2m, const float* __restrict__ qc,
    const float* __restrict__ kTc, const float* __restrict__ vc,
    const float* __restrict__ nf, const float* __restrict__ Wo,
    const float* __restrict__ bo, const float* __restrict__ gamma,
    const float* __restrict__ beta, float* __restrict__ out) {
  int x = blockIdx.x;
  int b = x & 1, ci = x >> 1;
  int nv = cnt[b];
  int t = threadIdx.x;

  if (ci >= nv) {                       // masked node -> x==0 -> LN gives beta
    int node = b * NB + mlist[b * NB + (ci - nv)];
    out[(size_t)node * NODE_DIM + t] = beta[t];
    return;
  }
  int node = b * NB + vlist[b * NB + ci];
  int slot = b * NB + ci;

  __shared__ f16  sE0[HEADS][SEP];      // dot + c-half0 bias; later softmax w
  __shared__ f16  sE1[HEADS][SEP];      // c-half1 bias (pure store)
  __shared__ __align__(16) float qs[HIDDEN];
  __shared__ float invs[HEADS];
  __shared__ float partD[8][HIDDEN];
  __shared__ __align__(16) float aggL[HIDDEN];
  __shared__ float red[2][4];

  if (t < HIDDEN) qs[t] = qc[(size_t)slot * HIDDEN + t];
  float pix = pcx[slot], piy = pcy[slot];
  __syncthreads();

  // ---- A: qk dots, float4 over keys (8 heads x 32 lanes) ----
  {
    int h = t >> 5, l = t & 31;
    const float* kb = kTc + ((size_t)b * HIDDEN + h * 16) * NB;
    float qv[16];
#pragma unroll
    for (int r = 0; r < 16; ++r) qv[r] = qs[h * 16 + r];
    float bh = b2m[h];
    int nvp4 = (nv + 3) >> 2;
    for (int j4 = l; j4 < nvp4; j4 += 32) {
      float4 acc = {0.f, 0.f, 0.f, 0.f};
#pragma unroll
      for (int r = 0; r < 16; ++r) {
        float4 kv = ((const float4*)(kb + (size_t)r * NB))[j4];
        acc.x = fmaf(qv[r], kv.x, acc.x);
        acc.y = fmaf(qv[r], kv.y, acc.y);
        acc.z = fmaf(qv[r], kv.z, acc.z);
        acc.w = fmaf(qv[r], kv.w, acc.w);
      }
      sE0[h][4 * j4 + 0] = (f16)fmaf(acc.x, 0.25f, bh);
      sE0[h][4 * j4 + 1] = (f16)fmaf(acc.y, 0.25f, bh);
      sE0[h][4 * j4 + 2] = (f16)fmaf(acc.z, 0.25f, bh);
      sE0[h][4 * j4 + 3] = (f16)fmaf(acc.w, 0.25f, bh);
    }
  }
  __syncthreads();

  // ---- B: edge-MLP bias; 128 key-lanes x 2 c-halves, 3 key-slots/thread ----
  {
    int kk = t & 127, ch = t >> 7;
    int cb = ch * 64;
    for (int base = 0; base < nv; base += 384) {
      int k0 = base + kk;
      if (k0 >= nv) continue;           // tail chunk: skip dead lanes entirely
      int k1 = k0 + 128, k2 = k0 + 256;
      bool v1 = k1 < nv, v2 = k2 < nv;
      int s0 = b * NB + k0;
      int s1 = b * NB + (v1 ? k1 : k0);
      int s2 = b * NB + (v2 ? k2 : k0);
      float ux0, uy0, dd0, ux1, uy1, dd1, ux2, uy2, dd2;
      {
        float dx = pix - pcx[s0], dy = piy - pcy[s0];
        float sq = dx * dx + dy * dy;
        dd0 = sqrtf(sq + 1e-6f);
        float dn = fmaxf(sqrtf(sq), 1e-6f);
        ux0 = dx / dn; uy0 = dy / dn;
      }
      {
        float dx = pix - pcx[s1], dy = piy - pcy[s1];
        float sq = dx * dx + dy * dy;
        dd1 = sqrtf(sq + 1e-6f);
        float dn = fmaxf(sqrtf(sq), 1e-6f);
        ux1 = dx / dn; uy1 = dy / dn;
      }
      {
        float dx = pix - pcx[s2], dy = piy - pcy[s2];
        float sq = dx * dx + dy * dy;
        dd2 = sqrtf(sq + 1e-6f);
        float dn = fmaxf(sqrtf(sq), 1e-6f);
        ux2 = dx / dn; uy2 = dy / dn;
      }
      float bias0[8] = {}, bias1[8] = {}, bias2[8] = {};
#pragma unroll 4
      for (int c = cb; c < cb + 64; ++c) {
        const float4* Pc = (const float4*)(P + c * 12);  // uniform -> s_load_x4
        float4 p0 = Pc[0], p1 = Pc[1], p2 = Pc[2];
        float g0 = gelu_f(fmaf(ux0, p0.x, fmaf(uy0, p0.y, fmaf(dd0, p0.z, p0.w))));
        float g1 = gelu_f(fmaf(ux1, p0.x, fmaf(uy1, p0.y, fmaf(dd1, p0.z, p0.w))));
        float g2 = gelu_f(fmaf(ux2, p0.x, fmaf(uy2, p0.y, fmaf(dd2, p0.z, p0.w))));
        bias0[0]=fmaf(g0,p1.x,bias0[0]); bias1[0]=fmaf(g1,p1.x,bias1[0]); bias2[0]=fmaf(g2,p1.x,bias2[0]);
        bias0[1]=fmaf(g0,p1.y,bias0[1]); bias1[1]=fmaf(g1,p1.y,bias1[1]); bias2[1]=fmaf(g2,p1.y,bias2[1]);
        bias0[2]=fmaf(g0,p1.z,bias0[2]); bias1[2]=fmaf(g1,p1.z,bias1[2]); bias2[2]=fmaf(g2,p1.z,bias2[2]);
        bias0[3]=fmaf(g0,p1.w,bias0[3]); bias1[3]=fmaf(g1,p1.w,bias1[3]); bias2[3]=fmaf(g2,p1.w,bias2[3]);
        bias0[4]=fmaf(g0,p2.x,bias0[4]); bias1[4]=fmaf(g1,p2.x,bias1[4]); bias2[4]=fmaf(g2,p2.x,bias2[4]);
        bias0[5]=fmaf(g0,p2.y,bias0[5]); bias1[5]=fmaf(g1,p2.y,bias1[5]); bias2[5]=fmaf(g2,p2.y,bias2[5]);
        bias0[6]=fmaf(g0,p2.z,bias0[6]); bias1[6]=fmaf(g1,p2.z,bias1[6]); bias2[6]=fmaf(g2,p2.z,bias2[6]);
        bias0[7]=fmaf(g0,p2.w,bias0[7]); bias1[7]=fmaf(g1,p2.w,bias1[7]); bias2[7]=fmaf(g2,p2.w,bias2[7]);
      }
      if (ch == 0) {                    // RMW own array (no cross-half race)
#pragma unroll
        for (int h = 0; h < 8; ++h) sE0[h][k0] = (f16)((float)sE0[h][k0] + bias0[h]);
        if (v1) {
#pragma unroll
          for (int h = 0; h < 8; ++h) sE0[h][k1] = (f16)((float)sE0[h][k1] + bias1[h]);
        }
        if (v2) {
#pragma unroll
          for (int h = 0; h < 8; ++h) sE0[h][k2] = (f16)((float)sE0[h][k2] + bias2[h]);
        }
      } else {                          // pure store into sE1
#pragma unroll
        for (int h = 0; h < 8; ++h) sE1[h][k0] = (f16)bias0[h];
        if (v1) {
#pragma unroll
          for (int h = 0; h < 8; ++h) sE1[h][k1] = (f16)bias1[h];
        }
        if (v2) {
#pragma unroll
          for (int h = 0; h < 8; ++h) sE1[h][k2] = (f16)bias2[h];
        }
      }
    }
  }
  __syncthreads();

  // ---- C: softmax per head over sE0+sE1; store w back to sE0 ----
  {
    int h = t >> 5, l = t & 31;
    float m = -FLT_MAX;
    for (int jj = l; jj < nv; jj += 32)
      m = fmaxf(m, (float)sE0[h][jj] + (float)sE1[h][jj]);
    for (int off = 16; off; off >>= 1) m = fmaxf(m, __shfl_down(m, off, 32));
    m = __shfl(m, 0, 32);
    float s = 0.0f;
    for (int jj = l; jj < nv; jj += 32) {
      float e = __expf((float)sE0[h][jj] + (float)sE1[h][jj] - m);
      sE0[h][jj] = (f16)e;
      s += e;
    }
    for (int off = 16; off; off >>= 1) s += __shfl_down(s, off, 32);
    if (l == 0) invs[h] = 1.0f / s;
  }
  __syncthreads();

  // ---- D: weighted V accumulation, float4 over channels, 8 key-groups ----
  {
    int o4 = t & 31, g = t >> 3 >> 2;   // g = t>>5
    g = t >> 5;
    int h = o4 >> 2;
    float4 acc = {0.f, 0.f, 0.f, 0.f};
    for (int jj = g; jj < nv; jj += 8) {
      float w = (float)sE0[h][jj];
      float4 vv = ((const float4*)(vc + ((size_t)(b * NB + jj)) * HIDDEN))[o4];
      acc.x = fmaf(w, vv.x, acc.x);
      acc.y = fmaf(w, vv.y, acc.y);
      acc.z = fmaf(w, vv.z, acc.z);
      acc.w = fmaf(w, vv.w, acc.w);
    }
    ((float4*)&partD[g][o4 * 4])[0] = acc;
  }
  __syncthreads();
  if (t < HIDDEN) {
    float s = 0.0f;
#pragma unroll
    for (int g = 0; g < 8; ++g) s += partD[g][t];
    aggL[t] = s * invs[t >> 4];
  }
  __syncthreads();

  // ---- E: out projection + residual + LayerNorm ----
  {
    float y0 = bo[t], y1 = 0.f, y2 = 0.f, y3 = 0.f;
    const float4* a4 = (const float4*)aggL;
#pragma unroll 4
    for (int kg = 0; kg < 32; ++kg) {
      float4 a = a4[kg];                               // ds_read_b128 broadcast
      y0 = fmaf(a.x, Wo[(4 * kg + 0) * NODE_DIM + t], y0);
      y1 = fmaf(a.y, Wo[(4 * kg + 1) * NODE_DIM + t], y1);
      y2 = fmaf(a.z, Wo[(4 * kg + 2) * NODE_DIM + t], y2);
      y3 = fmaf(a.w, Wo[(4 * kg + 3) * NODE_DIM + t], y3);
    }
    float y = (y0 + y1) + (y2 + y3);
    float xv = nf[(size_t)node * NODE_DIM + t] + y;
    float s = xv, s2 = xv * xv;
    for (int off = 32; off; off >>= 1) {
      s += __shfl_down(s, off, 64);
      s2 += __shfl_down(s2, off, 64);
    }
    if ((t & 63) == 0) { red[0][t >> 6] = s; red[1][t >> 6] = s2; }
    __syncthreads();
    s  = red[0][0] + red[0][1] + red[0][2] + red[0][3];
    s2 = red[1][0] + red[1][1] + red[1][2] + red[1][3];
    float mu = s * (1.0f / NODE_DIM);
    float var = fmaxf(s2 * (1.0f / NODE_DIM) - mu * mu, 0.0f);
    out[(size_t)node * NODE_DIM + t] =
        (xv - mu) * rsqrtf(var + 1e-5f) * gamma[t] + beta[t];
  }
}

extern "C" void kernel_launch(void* const* d_in, const int* in_sizes, int n_in,
                              void* d_out, int out_size, void* d_ws, size_t ws_size,
                              hipStream_t stream) {
  const float* nf    = (const float*)d_in[0];
  const float* pos   = (const float*)d_in[1];
  const int*   mask  = (const int*)  d_in[2];
  const float* Wq    = (const float*)d_in[3];
  const float* Wk    = (const float*)d_in[4];
  const float* Wv    = (const float*)d_in[5];
  const float* W1    = (const float*)d_in[6];
  const float* b1    = (const float*)d_in[7];
  const float* W2    = (const float*)d_in[8];
  const float* b2    = (const float*)d_in[9];
  const float* Wo    = (const float*)d_in[10];
  const float* bo    = (const float*)d_in[11];
  const float* gamma = (const float*)d_in[12];
  const float* beta  = (const float*)d_in[13];

  const int QKV = NNODES * HIDDEN;            // 196608

  float* ws   = (float*)d_ws;
  float* qc   = ws;
  float* kTc  = qc + QKV;
  float* vc   = kTc + QKV;
  float* P    = vc + QKV;                     // 1536
  float* b2m  = P + HIDDEN * 12;              // 8
  float* pcx  = b2m + 8;                      // 1536
  float* pcy  = pcx + NNODES;                 // 1536
  int*   cidx = (int*)(pcy + NNODES);         // 1536
  int*   vlist= cidx + NNODES;                // 1536
  int*   mlist= vlist + NNODES;               // 1536
  int*   cnt  = mlist + NNODES;               // 2

  setup_kernel<<<3,          256, 0, stream>>>(mask, pos, W1, b1, W2, b2,
                                               cnt, cidx, vlist, mlist,
                                               pcx, pcy, kTc, P, b2m);
  qkv_kernel  <<<NNODES / 2, 256, 0, stream>>>(nf, Wq, Wk, Wv, mask, cidx,
                                               qc, kTc, vc);
  attn_kernel <<<2 * NB,     256, 0, stream>>>(pcx, pcy, cnt, vlist, mlist,
                                               P, b2m, qc, kTc, vc,
                                               nf, Wo, bo, gamma, beta,
                                               (float*)d_out);
}